// Round 1
// baseline (329.287 us; speedup 1.0000x reference)
//
#include <hip/hip_runtime.h>

// ---------------------------------------------------------------------------
// Mamba-2 block (BATCH=2, SEQ=4096, DIM=1024, NH=16, HD=64, BLOCK=64)
// Pipeline:
//   1) x -> bf16; transpose wq/wk/wv/wo -> bf16 (N x K)
//   2) MFMA bf16 GEMM: xq/xk/xv = x @ w  (f32 out)
//   3) dt = softplus(x @ w_dt + b)  (f32 small GEMM)
//   4) RoPE(q,k) + X = v*dt  (in place)
//   5) SSD chunk kernel: Y_diag (overwrites X buffer), chunk_states, chunk totals
//   6) inter-chunk scan -> incoming states (reuses xk buffer) + final state -> d_out tail
//   7) Y_off kernel: Y = Y_diag + exp(cs)*C@S^T, written bf16 in scrambled layout
//   8) MFMA bf16 GEMM: out = y @ wo  (f32 into d_out)
// ---------------------------------------------------------------------------

typedef __bf16 bf16x8 __attribute__((ext_vector_type(8)));
typedef float f32x4 __attribute__((ext_vector_type(4)));
typedef unsigned int u32x4 __attribute__((ext_vector_type(4)));
typedef unsigned short u16x4 __attribute__((ext_vector_type(4)));

__device__ __forceinline__ unsigned short f2bf(float f) {
  unsigned int u = __builtin_bit_cast(unsigned int, f);
  u += 0x7fffu + ((u >> 16) & 1u);  // RNE
  return (unsigned short)(u >> 16);
}

// ---------------- convert f32 -> bf16 (vector) ----------------
__global__ __launch_bounds__(256) void convert_bf16_kernel(
    const float* __restrict__ in, unsigned short* __restrict__ out, int n4) {
  int g = blockIdx.x * 256 + threadIdx.x;
  if (g < n4) {
    f32x4 v = *reinterpret_cast<const f32x4*>(in + (size_t)g * 4);
    u16x4 o;
    o.x = f2bf(v.x); o.y = f2bf(v.y); o.z = f2bf(v.z); o.w = f2bf(v.w);
    *reinterpret_cast<u16x4*>(out + (size_t)g * 4) = o;
  }
}

// ---------------- transpose 1024x1024 f32 -> bf16 (N x K), 4 mats ----------------
__global__ __launch_bounds__(256) void transpose_w_kernel(
    const float* __restrict__ w0, const float* __restrict__ w1,
    const float* __restrict__ w2, const float* __restrict__ w3,
    unsigned short* __restrict__ wt) {
  __shared__ float tile[32][33];
  const int z = blockIdx.z;
  const float* w = (z == 0) ? w0 : (z == 1) ? w1 : (z == 2) ? w2 : w3;
  unsigned short* o = wt + (size_t)z * 1024 * 1024;
  const int bx = blockIdx.x, by = blockIdx.y;
  const int tx = threadIdx.x, ty = threadIdx.y;  // (32,8)
#pragma unroll
  for (int i = 0; i < 4; ++i)
    tile[ty + i * 8][tx] = w[(size_t)(by * 32 + ty + i * 8) * 1024 + bx * 32 + tx];
  __syncthreads();
#pragma unroll
  for (int i = 0; i < 4; ++i)
    o[(size_t)(bx * 32 + ty + i * 8) * 1024 + by * 32 + tx] = f2bf(tile[tx][ty + i * 8]);
}

// ---------------- bf16 MFMA GEMM: C(MxN f32) = A(MxK) @ Bt(NxK)^T ----------------
__global__ __launch_bounds__(256) void gemm_bf16_kernel(
    const unsigned short* __restrict__ A, const unsigned short* __restrict__ Bt,
    float* __restrict__ C, int M, int N, int K) {
  __shared__ unsigned short As[128][40];  // +8 pad: 2-way bank alias (free)
  __shared__ unsigned short Bs[128][40];
  const int tid = threadIdx.x;
  const int lane = tid & 63;
  const int wave = tid >> 6;
  const int wr = wave >> 1, wc = wave & 1;
  const int m0 = blockIdx.y * 128, n0 = blockIdx.x * 128;
  const int r0 = tid >> 2;         // 0..63
  const int ko = (tid & 3) * 8;    // 0,8,16,24
  const int lr = lane & 15;
  const int lk = (lane >> 4) * 8;
  f32x4 acc[4][4] = {};
  for (int kt = 0; kt < K; kt += 32) {
#pragma unroll
    for (int pass = 0; pass < 2; ++pass) {
      int r = r0 + pass * 64;
      u32x4 av = *reinterpret_cast<const u32x4*>(A + (size_t)(m0 + r) * K + kt + ko);
      u32x4 bv = *reinterpret_cast<const u32x4*>(Bt + (size_t)(n0 + r) * K + kt + ko);
      *reinterpret_cast<u32x4*>(&As[r][ko]) = av;
      *reinterpret_cast<u32x4*>(&Bs[r][ko]) = bv;
    }
    __syncthreads();
    bf16x8 aF[4], bF[4];
#pragma unroll
    for (int i = 0; i < 4; ++i) {
      aF[i] = *reinterpret_cast<const bf16x8*>(&As[wr * 64 + i * 16 + lr][lk]);
      bF[i] = *reinterpret_cast<const bf16x8*>(&Bs[wc * 64 + i * 16 + lr][lk]);
    }
#pragma unroll
    for (int i = 0; i < 4; ++i)
#pragma unroll
      for (int j = 0; j < 4; ++j)
        acc[i][j] = __builtin_amdgcn_mfma_f32_16x16x32_bf16(aF[i], bF[j], acc[i][j], 0, 0, 0);
    __syncthreads();
  }
  const int orow = m0 + wr * 64 + (lane >> 4) * 4;
  const int ocol = n0 + wc * 64 + lr;
#pragma unroll
  for (int i = 0; i < 4; ++i)
#pragma unroll
    for (int j = 0; j < 4; ++j)
#pragma unroll
      for (int r = 0; r < 4; ++r)
        C[(size_t)(orow + i * 16 + r) * N + ocol + j * 16] = acc[i][j][r];
}

// ---------------- dt = softplus(x @ w_dt + b) ----------------
__global__ __launch_bounds__(256) void dt_kernel(
    const float* __restrict__ x, const float* __restrict__ wdt,
    const float* __restrict__ bdt, float* __restrict__ dt) {
  const int row = blockIdx.x * 16 + (threadIdx.x >> 4);
  const int h = threadIdx.x & 15;
  const float* xr = x + (size_t)row * 1024;
  float acc = 0.f;
  for (int k = 0; k < 1024; k += 4) {
    f32x4 xv = *reinterpret_cast<const f32x4*>(xr + k);
    acc += xv.x * wdt[(k + 0) * 16 + h];
    acc += xv.y * wdt[(k + 1) * 16 + h];
    acc += xv.z * wdt[(k + 2) * 16 + h];
    acc += xv.w * wdt[(k + 3) * 16 + h];
  }
  acc += bdt[h];
  float sp = (acc > 0.f) ? (acc + log1pf(expf(-acc))) : log1pf(expf(acc));
  dt[(size_t)row * 16 + h] = sp;
}

// ---------------- RoPE(q,k) + X = v*dt, in place ----------------
__global__ __launch_bounds__(256) void rope_scale_kernel(
    float* __restrict__ xq, float* __restrict__ xk, float* __restrict__ xv,
    const float* __restrict__ cosb, const float* __restrict__ sinb,
    const float* __restrict__ dt) {
  const int g = blockIdx.x * 256 + threadIdx.x;  // 0 .. 8192*512-1
  const int d = g & 31;
  const int h = (g >> 5) & 15;
  const int row = g >> 9;
  const int l = row & 4095;
  const size_t i1 = (size_t)row * 1024 + h * 64 + d;
  const size_t i2 = i1 + 32;
  const float cv = cosb[(size_t)l * 64 + d];
  const float sv = sinb[(size_t)l * 64 + d];
  float q1 = xq[i1], q2 = xq[i2];
  xq[i1] = q1 * cv - q2 * sv;
  xq[i2] = q2 * cv + q1 * sv;
  float k1 = xk[i1], k2 = xk[i2];
  xk[i1] = k1 * cv - k2 * sv;
  xk[i2] = k2 * cv + k1 * sv;
  const float dtv = dt[(size_t)row * 16 + h];
  xv[i1] *= dtv;
  xv[i2] *= dtv;
}

// ---------------- SSD per-chunk: Y_diag, chunk states, totals ----------------
__global__ __launch_bounds__(256) void ssd_chunk_kernel(
    const float* __restrict__ Cmat, const float* __restrict__ Bmat,
    float* __restrict__ Xmat, const float* __restrict__ dt,
    const float* __restrict__ A_log, float* __restrict__ chunk_states,
    float* __restrict__ chunk_total) {
  __shared__ float Cs[64][68];  // C tile; later holds Gm = (C B^T) o L
  __shared__ float Bs[64][68];
  __shared__ float Xs[64][68];
  __shared__ float cs[64];
  __shared__ float dec[64];
  const int c = blockIdx.x, h = blockIdx.y, b = blockIdx.z;
  const int tid = threadIdx.x;
  const size_t base = ((size_t)(b * 4096 + c * 64)) * 1024 + h * 64;
  {
    const int rr = tid >> 4;
    const int col = (tid & 15) * 4;
#pragma unroll
    for (int p = 0; p < 4; ++p) {
      int r = rr + p * 16;
      size_t gofs = base + (size_t)r * 1024 + col;
      *reinterpret_cast<f32x4*>(&Cs[r][col]) = *reinterpret_cast<const f32x4*>(Cmat + gofs);
      *reinterpret_cast<f32x4*>(&Bs[r][col]) = *reinterpret_cast<const f32x4*>(Bmat + gofs);
      *reinterpret_cast<f32x4*>(&Xs[r][col]) = *reinterpret_cast<const f32x4*>(Xmat + gofs);
    }
  }
  if (tid < 64)
    cs[tid] = -expf(A_log[h]) * dt[((size_t)(b * 4096 + c * 64 + tid)) * 16 + h];
  __syncthreads();
  if (tid == 0) {
    float run = 0.f;
    for (int s = 0; s < 64; ++s) { run += cs[s]; cs[s] = run; }
  }
  __syncthreads();
  if (tid < 64) dec[tid] = expf(cs[63] - cs[tid]);
  const int ty = tid >> 4, tx = tid & 15;
  float g[4][4] = {};
  for (int n = 0; n < 64; ++n) {
    float cv[4], bv[4];
#pragma unroll
    for (int i = 0; i < 4; ++i) cv[i] = Cs[ty * 4 + i][n];
#pragma unroll
    for (int j = 0; j < 4; ++j) bv[j] = Bs[tx * 4 + j][n];
#pragma unroll
    for (int i = 0; i < 4; ++i)
#pragma unroll
      for (int j = 0; j < 4; ++j) g[i][j] += cv[i] * bv[j];
  }
  __syncthreads();  // all reads of Cs done; dec ready
#pragma unroll
  for (int i = 0; i < 4; ++i)
#pragma unroll
    for (int j = 0; j < 4; ++j) {
      int l = ty * 4 + i, s = tx * 4 + j;
      Cs[l][s] = (l >= s) ? g[i][j] * expf(cs[l] - cs[s]) : 0.f;
    }
  __syncthreads();
  float y[4][4] = {};
  float st[4][4] = {};
  for (int s = 0; s < 64; ++s) {
    float gv[4], xp[4];
#pragma unroll
    for (int i = 0; i < 4; ++i) gv[i] = Cs[ty * 4 + i][s];
#pragma unroll
    for (int j = 0; j < 4; ++j) xp[j] = Xs[s][tx * 4 + j];
#pragma unroll
    for (int i = 0; i < 4; ++i)
#pragma unroll
      for (int j = 0; j < 4; ++j) y[i][j] += gv[i] * xp[j];
    const float d = dec[s];
    float bv[4], xq2[4];
#pragma unroll
    for (int j = 0; j < 4; ++j) bv[j] = Bs[s][tx * 4 + j];        // n
#pragma unroll
    for (int i = 0; i < 4; ++i) xq2[i] = d * Xs[s][ty * 4 + i];   // p
#pragma unroll
    for (int i = 0; i < 4; ++i)
#pragma unroll
      for (int j = 0; j < 4; ++j) st[i][j] += xq2[i] * bv[j];
  }
#pragma unroll
  for (int i = 0; i < 4; ++i)
#pragma unroll
    for (int j = 0; j < 4; ++j)
      Xmat[base + (size_t)(ty * 4 + i) * 1024 + tx * 4 + j] = y[i][j];
  const size_t stbase = ((size_t)((b * 64 + c) * 16 + h)) * 4096;
#pragma unroll
  for (int i = 0; i < 4; ++i)
#pragma unroll
    for (int j = 0; j < 4; ++j)
      chunk_states[stbase + (ty * 4 + i) * 64 + tx * 4 + j] = st[i][j];
  if (tid == 0) chunk_total[(b * 16 + h) * 64 + c] = cs[63];
}

// ---------------- inter-chunk scan ----------------
__global__ __launch_bounds__(256) void scan_kernel(
    const float* __restrict__ chunk_states, const float* __restrict__ chunk_total,
    float* __restrict__ inc_states, float* __restrict__ state_out) {
  const int g = blockIdx.x * 256 + threadIdx.x;  // 0..131071
  const int n = g & 63;
  const int p = (g >> 6) & 63;
  const int h = (g >> 12) & 15;
  const int b = g >> 16;
  const size_t pn = (size_t)p * 64 + n;
  float inc = 0.f;
  for (int c = 0; c < 64; ++c) {
    const size_t idx = ((size_t)((b * 64 + c) * 16 + h)) * 4096 + pn;
    inc_states[idx] = inc;
    const float d = expf(chunk_total[(b * 16 + h) * 64 + c]);
    inc = d * inc + chunk_states[idx];
  }
  state_out[((size_t)(b * 16 + h) * 64 + p) * 64 + n] = inc;
}

// ---------------- Y_off + scrambled bf16 y ----------------
__global__ __launch_bounds__(256) void y_off_kernel(
    const float* __restrict__ Cmat, const float* __restrict__ inc_states,
    const float* __restrict__ ydiag, const float* __restrict__ dt,
    const float* __restrict__ A_log, unsigned short* __restrict__ y_bf) {
  __shared__ float Cs[64][68];
  __shared__ float Ss[64][68];
  __shared__ float cs[64];
  __shared__ float sde[64];
  const int c = blockIdx.x, h = blockIdx.y, b = blockIdx.z;
  const int tid = threadIdx.x;
  const size_t base = ((size_t)(b * 4096 + c * 64)) * 1024 + h * 64;
  const size_t stbase = ((size_t)((b * 64 + c) * 16 + h)) * 4096;
  {
    const int rr = tid >> 4;
    const int col = (tid & 15) * 4;
#pragma unroll
    for (int p = 0; p < 4; ++p) {
      int r = rr + p * 16;
      *reinterpret_cast<f32x4*>(&Cs[r][col]) =
          *reinterpret_cast<const f32x4*>(Cmat + base + (size_t)r * 1024 + col);
      *reinterpret_cast<f32x4*>(&Ss[r][col]) =
          *reinterpret_cast<const f32x4*>(inc_states + stbase + (size_t)r * 64 + col);
    }
  }
  if (tid < 64)
    cs[tid] = -expf(A_log[h]) * dt[((size_t)(b * 4096 + c * 64 + tid)) * 16 + h];
  __syncthreads();
  if (tid == 0) {
    float run = 0.f;
    for (int s = 0; s < 64; ++s) { run += cs[s]; cs[s] = run; }
  }
  __syncthreads();
  if (tid < 64) sde[tid] = expf(cs[tid]);
  const int ty = tid >> 4, tx = tid & 15;
  float o[4][4] = {};
  for (int n = 0; n < 64; ++n) {
    float cv[4], sv[4];
#pragma unroll
    for (int i = 0; i < 4; ++i) cv[i] = Cs[ty * 4 + i][n];
#pragma unroll
    for (int j = 0; j < 4; ++j) sv[j] = Ss[tx * 4 + j][n];
#pragma unroll
    for (int i = 0; i < 4; ++i)
#pragma unroll
      for (int j = 0; j < 4; ++j) o[i][j] += cv[i] * sv[j];
  }
  __syncthreads();  // sde visible to all
#pragma unroll
  for (int i = 0; i < 4; ++i)
#pragma unroll
    for (int j = 0; j < 4; ++j) {
      const int l = ty * 4 + i, p = tx * 4 + j;
      const float v = ydiag[base + (size_t)l * 1024 + p] + sde[l] * o[i][j];
      const size_t orow = (size_t)(b * 4096 + h * 256 + c * 4 + (l >> 4));
      y_bf[orow * 1024 + (l & 15) * 64 + p] = f2bf(v);
    }
}

// ---------------------------------------------------------------------------
extern "C" void kernel_launch(void* const* d_in, const int* in_sizes, int n_in,
                              void* d_out, int out_size, void* d_ws, size_t ws_size,
                              hipStream_t stream) {
  (void)in_sizes; (void)n_in; (void)out_size; (void)ws_size;
  const float* x = (const float*)d_in[0];
  const float* cosb = (const float*)d_in[1];
  const float* sinb = (const float*)d_in[2];
  const float* wq = (const float*)d_in[3];
  const float* wk = (const float*)d_in[4];
  const float* wv = (const float*)d_in[5];
  const float* wo = (const float*)d_in[6];
  const float* A_log = (const float*)d_in[7];
  const float* wdt = (const float*)d_in[8];
  const float* bdt = (const float*)d_in[9];

  float* out_y = (float*)d_out;                 // (2,4096,1024) f32
  float* out_state = out_y + 8388608;           // (2,16,64,64) f32

  char* ws = (char*)d_ws;
  unsigned short* x_bf = (unsigned short*)(ws);                 // 16 MiB (reused as y_bf)
  unsigned short* w_t = (unsigned short*)(ws + 16777216);       // 8 MiB (4 x 1024x1024 bf16)
  float* xq = (float*)(ws + 25165824);                          // 32 MiB
  float* xk = (float*)(ws + 58720256);                          // 32 MiB (reused as inc_states)
  float* xv = (float*)(ws + 92274688);                          // 32 MiB (X, then Y_diag)
  float* dtb = (float*)(ws + 125829120);                        // 0.5 MiB
  float* chunk_states = (float*)(ws + 126353408);               // 32 MiB
  float* chunk_total = (float*)(ws + 159907840);                // 8 KiB

  convert_bf16_kernel<<<8192, 256, 0, stream>>>(x, x_bf, 2097152);
  transpose_w_kernel<<<dim3(32, 32, 4), dim3(32, 8), 0, stream>>>(wq, wk, wv, wo, w_t);

  dim3 ggrid(8, 64);  // N/128, M/128
  gemm_bf16_kernel<<<ggrid, 256, 0, stream>>>(x_bf, w_t + 0 * 1048576, xq, 8192, 1024, 1024);
  gemm_bf16_kernel<<<ggrid, 256, 0, stream>>>(x_bf, w_t + 1 * 1048576, xk, 8192, 1024, 1024);
  gemm_bf16_kernel<<<ggrid, 256, 0, stream>>>(x_bf, w_t + 2 * 1048576, xv, 8192, 1024, 1024);

  dt_kernel<<<512, 256, 0, stream>>>(x, wdt, bdt, dtb);
  rope_scale_kernel<<<16384, 256, 0, stream>>>(xq, xk, xv, cosb, sinb, dtb);

  ssd_chunk_kernel<<<dim3(64, 16, 2), 256, 0, stream>>>(xq, xk, xv, dtb, A_log,
                                                        chunk_states, chunk_total);
  scan_kernel<<<512, 256, 0, stream>>>(chunk_states, chunk_total, xk /*inc_states*/, out_state);
  y_off_kernel<<<dim3(64, 16, 2), 256, 0, stream>>>(xq, xk /*inc_states*/, xv /*ydiag*/,
                                                    dtb, A_log, x_bf /*y_bf*/);

  gemm_bf16_kernel<<<ggrid, 256, 0, stream>>>(x_bf /*y_bf*/, w_t + 3 * 1048576, out_y,
                                              8192, 1024, 1024);
}

// Round 2
// 220.168 us; speedup vs baseline: 1.4956x; 1.4956x over previous
//
#include <hip/hip_runtime.h>

// ---------------------------------------------------------------------------
// Mamba-2 block (BATCH=2, SEQ=4096, DIM=1024, NH=16, HD=64, BLOCK=64)
//   1) x -> bf16; transpose wq/wk/wv/wo -> bf16 (N x K)
//   2) dt = softplus(x @ w_dt + b)
//   3) m97-style MFMA GEMMs with fused epilogues:
//        q_bf / k_bf = RoPE(x@w) bf16 ; xv_bf = (x@wv)*dt bf16
//   4) ssd_states (MFMA): chunk states + chunk decay
//   5) scan: inc states (bf16) + final state (f32 -> d_out tail)
//   6) ssd_y (MFMA): Y = (C@B^T . L)@X + (C.sde)@S^T, scrambled bf16 y
//   7) GEMM: out = y @ wo (f32 -> d_out)
// ---------------------------------------------------------------------------

typedef __bf16 bf16x8 __attribute__((ext_vector_type(8)));
typedef float f32x4 __attribute__((ext_vector_type(4)));
typedef unsigned int u32x4 __attribute__((ext_vector_type(4)));
typedef unsigned short u16x8 __attribute__((ext_vector_type(8)));
typedef unsigned short u16x4 __attribute__((ext_vector_type(4)));

__device__ __forceinline__ unsigned short f2bf(float f) {
  unsigned int u = __builtin_bit_cast(unsigned int, f);
  u += 0x7fffu + ((u >> 16) & 1u);  // RNE
  return (unsigned short)(u >> 16);
}
__device__ __forceinline__ float bf2f(unsigned short s) {
  unsigned int u = ((unsigned int)s) << 16;
  return __builtin_bit_cast(float, u);
}

#define GLOAD16(gp, lp)                                                \
  __builtin_amdgcn_global_load_lds(                                    \
      (const __attribute__((address_space(1))) void*)(gp),             \
      (__attribute__((address_space(3))) void*)(lp), 16, 0, 0)

// ---------------- convert f32 -> bf16 ----------------
__global__ __launch_bounds__(256) void convert_bf16_kernel(
    const float* __restrict__ in, unsigned short* __restrict__ out, int n4) {
  int g = blockIdx.x * 256 + threadIdx.x;
  if (g < n4) {
    f32x4 v = *reinterpret_cast<const f32x4*>(in + (size_t)g * 4);
    u16x4 o;
    o.x = f2bf(v.x); o.y = f2bf(v.y); o.z = f2bf(v.z); o.w = f2bf(v.w);
    *reinterpret_cast<u16x4*>(out + (size_t)g * 4) = o;
  }
}

// ---------------- transpose 1024x1024 f32 -> bf16 (N x K), 4 mats ----------------
__global__ __launch_bounds__(256) void transpose_w_kernel(
    const float* __restrict__ w0, const float* __restrict__ w1,
    const float* __restrict__ w2, const float* __restrict__ w3,
    unsigned short* __restrict__ wt) {
  __shared__ float tile[32][33];
  const int z = blockIdx.z;
  const float* w = (z == 0) ? w0 : (z == 1) ? w1 : (z == 2) ? w2 : w3;
  unsigned short* o = wt + (size_t)z * 1024 * 1024;
  const int bx = blockIdx.x, by = blockIdx.y;
  const int tx = threadIdx.x, ty = threadIdx.y;  // (32,8)
#pragma unroll
  for (int i = 0; i < 4; ++i)
    tile[ty + i * 8][tx] = w[(size_t)(by * 32 + ty + i * 8) * 1024 + bx * 32 + tx];
  __syncthreads();
#pragma unroll
  for (int i = 0; i < 4; ++i)
    o[(size_t)(bx * 32 + ty + i * 8) * 1024 + by * 32 + tx] = f2bf(tile[tx][ty + i * 8]);
}

// ---------------- dt = softplus(x @ w_dt + b) ----------------
__global__ __launch_bounds__(256) void dt_kernel(
    const float* __restrict__ x, const float* __restrict__ wdt,
    const float* __restrict__ bdt, float* __restrict__ dt) {
  const int row = blockIdx.x * 16 + (threadIdx.x >> 4);
  const int h = threadIdx.x & 15;
  const float* xr = x + (size_t)row * 1024;
  float acc = 0.f;
  for (int k = 0; k < 1024; k += 4) {
    f32x4 xv = *reinterpret_cast<const f32x4*>(xr + k);
    acc += xv.x * wdt[(k + 0) * 16 + h];
    acc += xv.y * wdt[(k + 1) * 16 + h];
    acc += xv.z * wdt[(k + 2) * 16 + h];
    acc += xv.w * wdt[(k + 3) * 16 + h];
  }
  acc += bdt[h];
  float sp = (acc > 0.f) ? (acc + log1pf(expf(-acc))) : log1pf(expf(acc));
  dt[(size_t)row * 16 + h] = sp;
}

// ---------------- m97-style bf16 GEMM, M=8192 N=1024 K=1024 ----------------
// EPI: 0 = plain f32 out; 1 = RoPE -> bf16; 2 = *dt -> bf16
template <int EPI>
__global__ __launch_bounds__(256) void gemm128_kernel(
    const unsigned short* __restrict__ A, const unsigned short* __restrict__ Bt,
    void* __restrict__ outp, const float* __restrict__ cosb,
    const float* __restrict__ sinb, const float* __restrict__ dtb) {
  __shared__ unsigned short As[128 * 32];
  __shared__ unsigned short Bs[128 * 32];
  const int tid = threadIdx.x, lane = tid & 63, w = tid >> 6;
  const int m0 = blockIdx.y * 128, n0 = blockIdx.x * 128;
  const int srow = w * 32 + (lane >> 2);
  const int scol = (lane & 3) * 8;
  const unsigned short* ga = A + (size_t)(m0 + srow) * 1024 + scol;
  const unsigned short* gb = Bt + (size_t)(n0 + srow) * 1024 + scol;
  unsigned short* la = As + (w * 32) * 32;  // wave-uniform LDS base
  unsigned short* lb = Bs + (w * 32) * 32;
  const int lr = lane & 15, lk = (lane >> 4) * 8;
  const int wr = w >> 1, wc = w & 1;
  f32x4 acc[4][4] = {};
  for (int kt = 0; kt < 1024; kt += 32) {
    GLOAD16(ga + kt, la);
    GLOAD16(ga + kt + (size_t)16 * 1024, la + 16 * 32);
    GLOAD16(gb + kt, lb);
    GLOAD16(gb + kt + (size_t)16 * 1024, lb + 16 * 32);
    __syncthreads();
    bf16x8 aF[4], bF[4];
#pragma unroll
    for (int i = 0; i < 4; ++i) {
      aF[i] = *reinterpret_cast<const bf16x8*>(&As[(wr * 64 + i * 16 + lr) * 32 + lk]);
      bF[i] = *reinterpret_cast<const bf16x8*>(&Bs[(wc * 64 + i * 16 + lr) * 32 + lk]);
    }
#pragma unroll
    for (int i = 0; i < 4; ++i)
#pragma unroll
      for (int j = 0; j < 4; ++j)
        acc[i][j] = __builtin_amdgcn_mfma_f32_16x16x32_bf16(aF[i], bF[j], acc[i][j], 0, 0, 0);
    __syncthreads();
  }
  const int r0 = m0 + wr * 64 + ((lane >> 4) << 2);
  const int c0 = n0 + wc * 64 + lr;
  if constexpr (EPI == 0) {
    float* O = (float*)outp;
#pragma unroll
    for (int i = 0; i < 4; ++i)
#pragma unroll
      for (int j = 0; j < 4; ++j)
#pragma unroll
        for (int r = 0; r < 4; ++r)
          O[(size_t)(r0 + i * 16 + r) * 1024 + c0 + j * 16] = acc[i][j][r];
  } else if constexpr (EPI == 1) {
    unsigned short* O = (unsigned short*)outp;
#pragma unroll
    for (int i = 0; i < 4; ++i)
#pragma unroll
      for (int jj = 0; jj < 2; ++jj) {
        const int d1 = jj * 16 + lr;  // 0..31; cos[d]==cos[d+32]
#pragma unroll
        for (int r = 0; r < 4; ++r) {
          const int row = r0 + i * 16 + r;
          const int l = row & 4095;
          const float cv = cosb[(size_t)l * 64 + d1];
          const float sv = sinb[(size_t)l * 64 + d1];
          const float v1 = acc[i][jj][r], v2 = acc[i][jj + 2][r];
          O[(size_t)row * 1024 + c0 + jj * 16] = f2bf(v1 * cv - v2 * sv);
          O[(size_t)row * 1024 + c0 + jj * 16 + 32] = f2bf(v2 * cv + v1 * sv);
        }
      }
  } else {
    unsigned short* O = (unsigned short*)outp;
    const int h = (n0 + wc * 64) >> 6;
#pragma unroll
    for (int i = 0; i < 4; ++i)
#pragma unroll
      for (int r = 0; r < 4; ++r) {
        const int row = r0 + i * 16 + r;
        const float dtv = dtb[(size_t)row * 16 + h];
#pragma unroll
        for (int j = 0; j < 4; ++j)
          O[(size_t)row * 1024 + c0 + j * 16] = f2bf(acc[i][j][r] * dtv);
      }
  }
}

// ---------------- SSD pre-scan: chunk states (MFMA) ----------------
__global__ __launch_bounds__(256) void ssd_states_kernel(
    const unsigned short* __restrict__ Kb, const unsigned short* __restrict__ Xb,
    const float* __restrict__ dtb, const float* __restrict__ A_log,
    float* __restrict__ chunk_states, float* __restrict__ chunk_dec) {
  __shared__ unsigned short T1[64 * 72], T2[64 * 72];   // B, X row-major
  __shared__ unsigned short BtL[64 * 72], XdL[64 * 72]; // transposed (k = s)
  __shared__ float csL[64], decL[64];
  const int c = blockIdx.x, h = blockIdx.y, b = blockIdx.z;
  const int tid = threadIdx.x, lane = tid & 63, w = tid >> 6;
  const size_t gbase = ((size_t)(b * 4096 + c * 64)) * 1024 + h * 64;
  {
    const int s = tid >> 2, e0 = (tid & 3) * 16;
    const unsigned short* gk = Kb + gbase + (size_t)s * 1024 + e0;
    const unsigned short* gx = Xb + gbase + (size_t)s * 1024 + e0;
    *(u32x4*)&T1[s * 72 + e0] = *(const u32x4*)gk;
    *(u32x4*)&T1[s * 72 + e0 + 8] = *(const u32x4*)(gk + 8);
    *(u32x4*)&T2[s * 72 + e0] = *(const u32x4*)gx;
    *(u32x4*)&T2[s * 72 + e0 + 8] = *(const u32x4*)(gx + 8);
  }
  if (w == 0) {
    float a = -expf(A_log[h]) * dtb[((size_t)(b * 4096 + c * 64 + lane)) * 16 + h];
    float v = a;
#pragma unroll
    for (int d = 1; d < 64; d <<= 1) {
      float o = __shfl_up(v, d, 64);
      if (lane >= d) v += o;
    }
    const float tot = __shfl(v, 63, 64);
    csL[lane] = v;
    decL[lane] = expf(tot - v);
    if (lane == 0) chunk_dec[((size_t)(b * 16 + h)) * 64 + c] = expf(tot);
  }
  __syncthreads();
#pragma unroll
  for (int q = 0; q < 2; ++q) {  // transpose with dec fold-in
    const int p = lane;
    const int s0 = (q * 4 + w) * 8;
    u16x8 vb, vx;
#pragma unroll
    for (int j = 0; j < 8; ++j) {
      vb[j] = T1[(s0 + j) * 72 + p];
      vx[j] = f2bf(bf2f(T2[(s0 + j) * 72 + p]) * decL[s0 + j]);
    }
    *(u16x8*)&BtL[p * 72 + s0] = vb;
    *(u16x8*)&XdL[p * 72 + s0] = vx;
  }
  __syncthreads();
  const int lr = lane & 15, lk = (lane >> 4) * 8;
  f32x4 acc[4] = {};
#pragma unroll
  for (int kt = 0; kt < 64; kt += 32) {
    bf16x8 aF = *reinterpret_cast<const bf16x8*>(&XdL[(w * 16 + lr) * 72 + kt + lk]);
#pragma unroll
    for (int j = 0; j < 4; ++j) {
      bf16x8 bF = *reinterpret_cast<const bf16x8*>(&BtL[(j * 16 + lr) * 72 + kt + lk]);
      acc[j] = __builtin_amdgcn_mfma_f32_16x16x32_bf16(aF, bF, acc[j], 0, 0, 0);
    }
  }
  const size_t stb = ((size_t)((b * 64 + c) * 16 + h)) * 4096;
#pragma unroll
  for (int j = 0; j < 4; ++j)
#pragma unroll
    for (int r = 0; r < 4; ++r)
      chunk_states[stb + (size_t)(w * 16 + (lane >> 4) * 4 + r) * 64 + j * 16 + lr] =
          acc[j][r];
}

// ---------------- inter-chunk scan ----------------
__global__ __launch_bounds__(256) void scan_kernel(
    const float* __restrict__ chunk_states, const float* __restrict__ chunk_dec,
    unsigned short* __restrict__ inc_bf, float* __restrict__ state_out) {
  const int g = blockIdx.x * 256 + threadIdx.x;
  const int n = g & 63, p = (g >> 6) & 63, h = (g >> 12) & 15, b = g >> 16;
  const size_t pn = (size_t)p * 64 + n;
  float inc = 0.f;
  for (int c = 0; c < 64; ++c) {
    const size_t idx = ((size_t)((b * 64 + c) * 16 + h)) * 4096 + pn;
    inc_bf[idx] = f2bf(inc);
    inc = chunk_dec[(b * 16 + h) * 64 + c] * inc + chunk_states[idx];
  }
  state_out[((size_t)(b * 16 + h) * 64 + p) * 64 + n] = inc;
}

// ---------------- SSD post-scan: Y = Gm@X + (C.sde)@S^T (MFMA) ----------------
__global__ __launch_bounds__(256) void ssd_y_kernel(
    const unsigned short* __restrict__ Qb, const unsigned short* __restrict__ Kb,
    const unsigned short* __restrict__ Xb, const unsigned short* __restrict__ Sg,
    const float* __restrict__ dtb, const float* __restrict__ A_log,
    unsigned short* __restrict__ y_bf) {
  __shared__ unsigned short Cb[64 * 72], Bb[64 * 72], Sb[64 * 72];
  __shared__ unsigned short Xt[64 * 72], TG[64 * 72];  // TG: X rm, then Gm
  __shared__ float csL[64], sdeL[64];
  const int c = blockIdx.x, h = blockIdx.y, b = blockIdx.z;
  const int tid = threadIdx.x, lane = tid & 63, w = tid >> 6;
  const size_t gbase = ((size_t)(b * 4096 + c * 64)) * 1024 + h * 64;
  const size_t sbase = ((size_t)((b * 64 + c) * 16 + h)) * 4096;
  {
    const int s = tid >> 2, e0 = (tid & 3) * 16;
    const unsigned short* gq = Qb + gbase + (size_t)s * 1024 + e0;
    const unsigned short* gk = Kb + gbase + (size_t)s * 1024 + e0;
    const unsigned short* gx = Xb + gbase + (size_t)s * 1024 + e0;
    const unsigned short* gs = Sg + sbase + (size_t)s * 64 + e0;
    *(u32x4*)&Cb[s * 72 + e0] = *(const u32x4*)gq;
    *(u32x4*)&Cb[s * 72 + e0 + 8] = *(const u32x4*)(gq + 8);
    *(u32x4*)&Bb[s * 72 + e0] = *(const u32x4*)gk;
    *(u32x4*)&Bb[s * 72 + e0 + 8] = *(const u32x4*)(gk + 8);
    *(u32x4*)&TG[s * 72 + e0] = *(const u32x4*)gx;
    *(u32x4*)&TG[s * 72 + e0 + 8] = *(const u32x4*)(gx + 8);
    *(u32x4*)&Sb[s * 72 + e0] = *(const u32x4*)gs;
    *(u32x4*)&Sb[s * 72 + e0 + 8] = *(const u32x4*)(gs + 8);
  }
  if (w == 0) {
    float a = -expf(A_log[h]) * dtb[((size_t)(b * 4096 + c * 64 + lane)) * 16 + h];
    float v = a;
#pragma unroll
    for (int d = 1; d < 64; d <<= 1) {
      float o = __shfl_up(v, d, 64);
      if (lane >= d) v += o;
    }
    csL[lane] = v;
    sdeL[lane] = expf(v);
  }
  __syncthreads();
  const int lr = lane & 15, lk = (lane >> 4) * 8;
  // G = C @ B^T (contract n)
  f32x4 g[4] = {};
#pragma unroll
  for (int kt = 0; kt < 64; kt += 32) {
    bf16x8 aF = *reinterpret_cast<const bf16x8*>(&Cb[(w * 16 + lr) * 72 + kt + lk]);
#pragma unroll
    for (int j = 0; j < 4; ++j) {
      bf16x8 bF = *reinterpret_cast<const bf16x8*>(&Bb[(j * 16 + lr) * 72 + kt + lk]);
      g[j] = __builtin_amdgcn_mfma_f32_16x16x32_bf16(aF, bF, g[j], 0, 0, 0);
    }
  }
  // transpose X: TG -> Xt
#pragma unroll
  for (int q = 0; q < 2; ++q) {
    const int p = lane;
    const int s0 = (q * 4 + w) * 8;
    u16x8 vx;
#pragma unroll
    for (int j = 0; j < 8; ++j) vx[j] = TG[(s0 + j) * 72 + p];
    *(u16x8*)&Xt[p * 72 + s0] = vx;
  }
  __syncthreads();
  // Gm = (G o L) -> TG ;  Cb *= sde[l]
#pragma unroll
  for (int j = 0; j < 4; ++j)
#pragma unroll
    for (int r = 0; r < 4; ++r) {
      const int l = w * 16 + (lane >> 4) * 4 + r;
      const int s = j * 16 + lr;
      const float gm = (l >= s) ? g[j][r] * expf(csL[l] - csL[s]) : 0.f;
      TG[l * 72 + s] = f2bf(gm);
    }
  {
    const int rl = tid >> 2, e0 = (tid & 3) * 16;
    const float sde = sdeL[rl];
#pragma unroll
    for (int half = 0; half < 2; ++half) {
      u16x8 v = *(u16x8*)&Cb[rl * 72 + e0 + half * 8];
#pragma unroll
      for (int j = 0; j < 8; ++j) v[j] = f2bf(bf2f(v[j]) * sde);
      *(u16x8*)&Cb[rl * 72 + e0 + half * 8] = v;
    }
  }
  __syncthreads();
  // Y = Gm @ Xt^T + Csde @ S^T
  f32x4 acc[4] = {};
#pragma unroll
  for (int kt = 0; kt < 64; kt += 32) {
    bf16x8 aG = *reinterpret_cast<const bf16x8*>(&TG[(w * 16 + lr) * 72 + kt + lk]);
    bf16x8 aC = *reinterpret_cast<const bf16x8*>(&Cb[(w * 16 + lr) * 72 + kt + lk]);
#pragma unroll
    for (int j = 0; j < 4; ++j) {
      bf16x8 bX = *reinterpret_cast<const bf16x8*>(&Xt[(j * 16 + lr) * 72 + kt + lk]);
      bf16x8 bS = *reinterpret_cast<const bf16x8*>(&Sb[(j * 16 + lr) * 72 + kt + lk]);
      acc[j] = __builtin_amdgcn_mfma_f32_16x16x32_bf16(aG, bX, acc[j], 0, 0, 0);
      acc[j] = __builtin_amdgcn_mfma_f32_16x16x32_bf16(aC, bS, acc[j], 0, 0, 0);
    }
  }
  // scrambled store: row = b*4096 + h*256 + c*4 + (l>>4), col = (l&15)*64 + p
  const size_t orow = (size_t)b * 4096 + h * 256 + c * 4 + w;
#pragma unroll
  for (int j = 0; j < 4; ++j)
#pragma unroll
    for (int r = 0; r < 4; ++r) {
      const int li = (lane >> 4) * 4 + r;
      y_bf[orow * 1024 + li * 64 + j * 16 + lr] = f2bf(acc[j][r]);
    }
}

// ---------------------------------------------------------------------------
extern "C" void kernel_launch(void* const* d_in, const int* in_sizes, int n_in,
                              void* d_out, int out_size, void* d_ws, size_t ws_size,
                              hipStream_t stream) {
  (void)in_sizes; (void)n_in; (void)out_size; (void)ws_size;
  const float* x = (const float*)d_in[0];
  const float* cosb = (const float*)d_in[1];
  const float* sinb = (const float*)d_in[2];
  const float* wq = (const float*)d_in[3];
  const float* wk = (const float*)d_in[4];
  const float* wv = (const float*)d_in[5];
  const float* wo = (const float*)d_in[6];
  const float* A_log = (const float*)d_in[7];
  const float* wdt = (const float*)d_in[8];
  const float* bdt = (const float*)d_in[9];

  float* out_y = (float*)d_out;        // (2,4096,1024) f32
  float* out_state = out_y + 8388608;  // (2,16,64,64) f32

  const size_t MBB = 1048576;
  char* ws = (char*)d_ws;
  unsigned short* x_bf = (unsigned short*)(ws);              // 16MB, reused as y_bf
  unsigned short* w_t = (unsigned short*)(ws + 16 * MBB);    // 8MB
  unsigned short* q_bf = (unsigned short*)(ws + 24 * MBB);   // 16MB
  unsigned short* k_bf = (unsigned short*)(ws + 40 * MBB);   // 16MB
  unsigned short* xv_bf = (unsigned short*)(ws + 56 * MBB);  // 16MB
  float* dtb = (float*)(ws + 72 * MBB);                      // 0.5MB
  float* chunk_states = (float*)(ws + 73 * MBB);             // 32MB
  float* chunk_dec = (float*)(ws + 105 * MBB);               // 8KB
  unsigned short* inc_bf = (unsigned short*)(ws + 106 * MBB);// 16MB

  convert_bf16_kernel<<<8192, 256, 0, stream>>>(x, x_bf, 2097152);
  transpose_w_kernel<<<dim3(32, 32, 4), dim3(32, 8), 0, stream>>>(wq, wk, wv, wo, w_t);
  dt_kernel<<<512, 256, 0, stream>>>(x, wdt, bdt, dtb);

  dim3 ggrid(8, 64);  // N/128, M/128
  gemm128_kernel<1><<<ggrid, 256, 0, stream>>>(x_bf, w_t + 0 * MBB, q_bf, cosb, sinb, nullptr);
  gemm128_kernel<1><<<ggrid, 256, 0, stream>>>(x_bf, w_t + 1 * MBB, k_bf, cosb, sinb, nullptr);
  gemm128_kernel<2><<<ggrid, 256, 0, stream>>>(x_bf, w_t + 2 * MBB, xv_bf, nullptr, nullptr, dtb);

  ssd_states_kernel<<<dim3(64, 16, 2), 256, 0, stream>>>(k_bf, xv_bf, dtb, A_log,
                                                         chunk_states, chunk_dec);
  scan_kernel<<<512, 256, 0, stream>>>(chunk_states, chunk_dec, inc_bf, out_state);
  ssd_y_kernel<<<dim3(64, 16, 2), 256, 0, stream>>>(q_bf, k_bf, xv_bf, inc_bf, dtb, A_log,
                                                    x_bf /*y_bf*/);

  gemm128_kernel<0><<<ggrid, 256, 0, stream>>>(x_bf /*y_bf*/, w_t + 3 * MBB, out_y,
                                               nullptr, nullptr, nullptr);
}

// Round 3
// 191.320 us; speedup vs baseline: 1.7211x; 1.1508x over previous
//
#include <hip/hip_runtime.h>

// ---------------------------------------------------------------------------
// Mamba-2 block (BATCH=2, SEQ=4096, DIM=1024, NH=16, HD=64, BLOCK=64)
//   1) x -> bf16; transpose wq/wk/wv/wo -> bf16 (N x K); wdt -> bf16 (16x1024)
//   2) dt = softplus(x_bf @ wdt^T + b)  [MFMA]
//   3) m97-style MFMA GEMMs with fused epilogues:
//        q_bf / k_bf = RoPE(x@w) bf16 ; xv_bf = (x@wv)*dt bf16
//   4) ssd_states (MFMA): chunk states (bf16) + chunk decay
//   5) scan: inc states (bf16) + final state (f32 -> d_out tail)
//   6) ssd_y (MFMA): Y = (C@B^T . L)@X + (C.sde)@S^T, scrambled bf16 y
//   7) GEMM: out = y @ wo (f32 -> d_out)
// ---------------------------------------------------------------------------

typedef __bf16 bf16x8 __attribute__((ext_vector_type(8)));
typedef float f32x4 __attribute__((ext_vector_type(4)));
typedef unsigned int u32x4 __attribute__((ext_vector_type(4)));
typedef unsigned short u16x8 __attribute__((ext_vector_type(8)));
typedef unsigned short u16x4 __attribute__((ext_vector_type(4)));

__device__ __forceinline__ unsigned short f2bf(float f) {
  unsigned int u = __builtin_bit_cast(unsigned int, f);
  u += 0x7fffu + ((u >> 16) & 1u);  // RNE
  return (unsigned short)(u >> 16);
}
__device__ __forceinline__ float bf2f(unsigned short s) {
  unsigned int u = ((unsigned int)s) << 16;
  return __builtin_bit_cast(float, u);
}

#define GLOAD16(gp, lp)                                                \
  __builtin_amdgcn_global_load_lds(                                    \
      (const __attribute__((address_space(1))) void*)(gp),             \
      (__attribute__((address_space(3))) void*)(lp), 16, 0, 0)

// ---------------- convert f32 -> bf16 ----------------
__global__ __launch_bounds__(256) void convert_bf16_kernel(
    const float* __restrict__ in, unsigned short* __restrict__ out, int n4) {
  int g = blockIdx.x * 256 + threadIdx.x;
  if (g < n4) {
    f32x4 v = *reinterpret_cast<const f32x4*>(in + (size_t)g * 4);
    u16x4 o;
    o.x = f2bf(v.x); o.y = f2bf(v.y); o.z = f2bf(v.z); o.w = f2bf(v.w);
    *reinterpret_cast<u16x4*>(out + (size_t)g * 4) = o;
  }
}

// ---------------- transpose 1024x1024 f32 -> bf16 (N x K), 4 mats ----------------
__global__ __launch_bounds__(256) void transpose_w_kernel(
    const float* __restrict__ w0, const float* __restrict__ w1,
    const float* __restrict__ w2, const float* __restrict__ w3,
    unsigned short* __restrict__ wt) {
  __shared__ float tile[32][33];
  const int z = blockIdx.z;
  const float* w = (z == 0) ? w0 : (z == 1) ? w1 : (z == 2) ? w2 : w3;
  unsigned short* o = wt + (size_t)z * 1024 * 1024;
  const int bx = blockIdx.x, by = blockIdx.y;
  const int tx = threadIdx.x, ty = threadIdx.y;  // (32,8)
#pragma unroll
  for (int i = 0; i < 4; ++i)
    tile[ty + i * 8][tx] = w[(size_t)(by * 32 + ty + i * 8) * 1024 + bx * 32 + tx];
  __syncthreads();
#pragma unroll
  for (int i = 0; i < 4; ++i)
    o[(size_t)(bx * 32 + ty + i * 8) * 1024 + by * 32 + tx] = f2bf(tile[tx][ty + i * 8]);
}

// ---------------- wdt (1024,16) f32 -> (16,1024) bf16 ----------------
__global__ __launch_bounds__(256) void wdt_t_kernel(
    const float* __restrict__ wdt, unsigned short* __restrict__ out) {
  const int g = blockIdx.x * 256 + threadIdx.x;  // 16384
  const int n = g >> 10, k = g & 1023;
  out[g] = f2bf(wdt[k * 16 + n]);
}

// ---------------- dt = softplus(x_bf @ wdt_t^T + b)  [MFMA] ----------------
__global__ __launch_bounds__(256) void dt_gemm_kernel(
    const unsigned short* __restrict__ A,   // 8192x1024 bf16
    const unsigned short* __restrict__ Bt,  // 16x1024 bf16
    const float* __restrict__ bdt, float* __restrict__ dt) {
  __shared__ unsigned short As[2 * 64 * 32];  // [kk][64][32]
  const int tid = threadIdx.x, lane = tid & 63, w = tid >> 6;
  const int m0 = blockIdx.x * 64;
  const unsigned short* ga =
      A + (size_t)(m0 + w * 16 + (lane >> 2)) * 1024 + (lane & 3) * 8;
  unsigned short* la = As + w * 512;  // wave-uniform base (elements)
  const int lr = lane & 15, lk = (lane >> 4) * 8;
  const unsigned short* gb = Bt + (size_t)lr * 1024 + lk;
  f32x4 acc = {};
  for (int kt = 0; kt < 1024; kt += 64) {
    GLOAD16(ga + kt, la);                 // k-half 0
    GLOAD16(ga + kt + 32, la + 2048);     // k-half 1
    bf16x8 bF0 = *reinterpret_cast<const bf16x8*>(gb + kt);
    bf16x8 bF1 = *reinterpret_cast<const bf16x8*>(gb + kt + 32);
    __syncthreads();
    bf16x8 aF0 = *reinterpret_cast<const bf16x8*>(&As[(w * 16 + lr) * 32 + lk]);
    bf16x8 aF1 = *reinterpret_cast<const bf16x8*>(&As[2048 + (w * 16 + lr) * 32 + lk]);
    acc = __builtin_amdgcn_mfma_f32_16x16x32_bf16(aF0, bF0, acc, 0, 0, 0);
    acc = __builtin_amdgcn_mfma_f32_16x16x32_bf16(aF1, bF1, acc, 0, 0, 0);
    __syncthreads();
  }
  const int h = lr;  // C/D: col = lane&15
  const float bv = bdt[h];
#pragma unroll
  for (int r = 0; r < 4; ++r) {
    const int row = m0 + w * 16 + (lane >> 4) * 4 + r;
    const float a = acc[r] + bv;
    const float sp = (a > 0.f) ? (a + log1pf(expf(-a))) : log1pf(expf(a));
    dt[(size_t)row * 16 + h] = sp;
  }
}

// ---------------- m97-style bf16 GEMM, M=8192 N=1024 K=1024 ----------------
// EPI: 0 = plain f32 out; 1 = RoPE -> bf16; 2 = *dt -> bf16
template <int EPI>
__global__ __launch_bounds__(256) void gemm128_kernel(
    const unsigned short* __restrict__ A, const unsigned short* __restrict__ Bt,
    void* __restrict__ outp, const float* __restrict__ cosb,
    const float* __restrict__ sinb, const float* __restrict__ dtb) {
  __shared__ unsigned short As[128 * 32];
  __shared__ unsigned short Bs[128 * 32];
  const int tid = threadIdx.x, lane = tid & 63, w = tid >> 6;
  const int m0 = blockIdx.y * 128, n0 = blockIdx.x * 128;
  const int srow = w * 32 + (lane >> 2);
  const int scol = (lane & 3) * 8;
  const unsigned short* ga = A + (size_t)(m0 + srow) * 1024 + scol;
  const unsigned short* gb = Bt + (size_t)(n0 + srow) * 1024 + scol;
  unsigned short* la = As + (w * 32) * 32;  // wave-uniform LDS base
  unsigned short* lb = Bs + (w * 32) * 32;
  const int lr = lane & 15, lk = (lane >> 4) * 8;
  const int wr = w >> 1, wc = w & 1;
  f32x4 acc[4][4] = {};
  for (int kt = 0; kt < 1024; kt += 32) {
    GLOAD16(ga + kt, la);
    GLOAD16(ga + kt + (size_t)16 * 1024, la + 16 * 32);
    GLOAD16(gb + kt, lb);
    GLOAD16(gb + kt + (size_t)16 * 1024, lb + 16 * 32);
    __syncthreads();
    bf16x8 aF[4], bF[4];
#pragma unroll
    for (int i = 0; i < 4; ++i) {
      aF[i] = *reinterpret_cast<const bf16x8*>(&As[(wr * 64 + i * 16 + lr) * 32 + lk]);
      bF[i] = *reinterpret_cast<const bf16x8*>(&Bs[(wc * 64 + i * 16 + lr) * 32 + lk]);
    }
#pragma unroll
    for (int i = 0; i < 4; ++i)
#pragma unroll
      for (int j = 0; j < 4; ++j)
        acc[i][j] = __builtin_amdgcn_mfma_f32_16x16x32_bf16(aF[i], bF[j], acc[i][j], 0, 0, 0);
    __syncthreads();
  }
  const int r0 = m0 + wr * 64 + ((lane >> 4) << 2);
  const int c0 = n0 + wc * 64 + lr;
  if constexpr (EPI == 0) {
    float* O = (float*)outp;
#pragma unroll
    for (int i = 0; i < 4; ++i)
#pragma unroll
      for (int j = 0; j < 4; ++j)
#pragma unroll
        for (int r = 0; r < 4; ++r)
          O[(size_t)(r0 + i * 16 + r) * 1024 + c0 + j * 16] = acc[i][j][r];
  } else if constexpr (EPI == 1) {
    unsigned short* O = (unsigned short*)outp;
#pragma unroll
    for (int i = 0; i < 4; ++i)
#pragma unroll
      for (int jj = 0; jj < 2; ++jj) {
        const int d1 = jj * 16 + lr;  // 0..31; cos[d]==cos[d+32]
#pragma unroll
        for (int r = 0; r < 4; ++r) {
          const int row = r0 + i * 16 + r;
          const int l = row & 4095;
          const float cv = cosb[(size_t)l * 64 + d1];
          const float sv = sinb[(size_t)l * 64 + d1];
          const float v1 = acc[i][jj][r], v2 = acc[i][jj + 2][r];
          O[(size_t)row * 1024 + c0 + jj * 16] = f2bf(v1 * cv - v2 * sv);
          O[(size_t)row * 1024 + c0 + jj * 16 + 32] = f2bf(v2 * cv + v1 * sv);
        }
      }
  } else {
    unsigned short* O = (unsigned short*)outp;
    const int h = (n0 + wc * 64) >> 6;
#pragma unroll
    for (int i = 0; i < 4; ++i)
#pragma unroll
      for (int r = 0; r < 4; ++r) {
        const int row = r0 + i * 16 + r;
        const float dtv = dtb[(size_t)row * 16 + h];
#pragma unroll
        for (int j = 0; j < 4; ++j)
          O[(size_t)row * 1024 + c0 + j * 16] = f2bf(acc[i][j][r] * dtv);
      }
  }
}

// ---------------- SSD pre-scan: chunk states (MFMA, bf16 out) ----------------
__global__ __launch_bounds__(256) void ssd_states_kernel(
    const unsigned short* __restrict__ Kb, const unsigned short* __restrict__ Xb,
    const float* __restrict__ dtb, const float* __restrict__ A_log,
    unsigned short* __restrict__ chunk_states, float* __restrict__ chunk_dec) {
  __shared__ unsigned short T1[64 * 72], T2[64 * 72];   // B, X row-major
  __shared__ unsigned short BtL[64 * 72], XdL[64 * 72]; // transposed (k = s)
  __shared__ float csL[64], decL[64];
  const int c = blockIdx.x, h = blockIdx.y, b = blockIdx.z;
  const int tid = threadIdx.x, lane = tid & 63, w = tid >> 6;
  const size_t gbase = ((size_t)(b * 4096 + c * 64)) * 1024 + h * 64;
  {
    const int s = tid >> 2, e0 = (tid & 3) * 16;
    const unsigned short* gk = Kb + gbase + (size_t)s * 1024 + e0;
    const unsigned short* gx = Xb + gbase + (size_t)s * 1024 + e0;
    *(u32x4*)&T1[s * 72 + e0] = *(const u32x4*)gk;
    *(u32x4*)&T1[s * 72 + e0 + 8] = *(const u32x4*)(gk + 8);
    *(u32x4*)&T2[s * 72 + e0] = *(const u32x4*)gx;
    *(u32x4*)&T2[s * 72 + e0 + 8] = *(const u32x4*)(gx + 8);
  }
  if (w == 0) {
    float a = -expf(A_log[h]) * dtb[((size_t)(b * 4096 + c * 64 + lane)) * 16 + h];
    float v = a;
#pragma unroll
    for (int d = 1; d < 64; d <<= 1) {
      float o = __shfl_up(v, d, 64);
      if (lane >= d) v += o;
    }
    const float tot = __shfl(v, 63, 64);
    csL[lane] = v;
    decL[lane] = expf(tot - v);
    if (lane == 0) chunk_dec[((size_t)(b * 16 + h)) * 64 + c] = expf(tot);
  }
  __syncthreads();
#pragma unroll
  for (int q = 0; q < 2; ++q) {  // transpose with dec fold-in
    const int p = lane;
    const int s0 = (q * 4 + w) * 8;
    u16x8 vb, vx;
#pragma unroll
    for (int j = 0; j < 8; ++j) {
      vb[j] = T1[(s0 + j) * 72 + p];
      vx[j] = f2bf(bf2f(T2[(s0 + j) * 72 + p]) * decL[s0 + j]);
    }
    *(u16x8*)&BtL[p * 72 + s0] = vb;
    *(u16x8*)&XdL[p * 72 + s0] = vx;
  }
  __syncthreads();
  const int lr = lane & 15, lk = (lane >> 4) * 8;
  f32x4 acc[4] = {};
#pragma unroll
  for (int kt = 0; kt < 64; kt += 32) {
    bf16x8 aF = *reinterpret_cast<const bf16x8*>(&XdL[(w * 16 + lr) * 72 + kt + lk]);
#pragma unroll
    for (int j = 0; j < 4; ++j) {
      bf16x8 bF = *reinterpret_cast<const bf16x8*>(&BtL[(j * 16 + lr) * 72 + kt + lk]);
      acc[j] = __builtin_amdgcn_mfma_f32_16x16x32_bf16(aF, bF, acc[j], 0, 0, 0);
    }
  }
  const size_t stb = ((size_t)((b * 64 + c) * 16 + h)) * 4096;
#pragma unroll
  for (int j = 0; j < 4; ++j)
#pragma unroll
    for (int r = 0; r < 4; ++r)
      chunk_states[stb + (size_t)(w * 16 + (lane >> 4) * 4 + r) * 64 + j * 16 + lr] =
          f2bf(acc[j][r]);
}

// ---------------- inter-chunk scan (bf16 states in, f32 accum) ----------------
__global__ __launch_bounds__(256) void scan_kernel(
    const unsigned short* __restrict__ chunk_states, const float* __restrict__ chunk_dec,
    unsigned short* __restrict__ inc_bf, float* __restrict__ state_out) {
  const int g = blockIdx.x * 256 + threadIdx.x;
  const int n = g & 63, p = (g >> 6) & 63, h = (g >> 12) & 15, b = g >> 16;
  const size_t pn = (size_t)p * 64 + n;
  float inc = 0.f;
  for (int c = 0; c < 64; ++c) {
    const size_t idx = ((size_t)((b * 64 + c) * 16 + h)) * 4096 + pn;
    inc_bf[idx] = f2bf(inc);
    inc = chunk_dec[(b * 16 + h) * 64 + c] * inc + bf2f(chunk_states[idx]);
  }
  state_out[((size_t)(b * 16 + h) * 64 + p) * 64 + n] = inc;
}

// ---------------- SSD post-scan: Y = Gm@X + (C.sde)@S^T (MFMA) ----------------
__global__ __launch_bounds__(256) void ssd_y_kernel(
    const unsigned short* __restrict__ Qb, const unsigned short* __restrict__ Kb,
    const unsigned short* __restrict__ Xb, const unsigned short* __restrict__ Sg,
    const float* __restrict__ dtb, const float* __restrict__ A_log,
    unsigned short* __restrict__ y_bf) {
  __shared__ unsigned short Cb[64 * 72], Bb[64 * 72], Sb[64 * 72];
  __shared__ unsigned short Xt[64 * 72], TG[64 * 72];  // TG: X rm, then Gm
  __shared__ float csL[64], sdeL[64];
  const int c = blockIdx.x, h = blockIdx.y, b = blockIdx.z;
  const int tid = threadIdx.x, lane = tid & 63, w = tid >> 6;
  const size_t gbase = ((size_t)(b * 4096 + c * 64)) * 1024 + h * 64;
  const size_t sbase = ((size_t)((b * 64 + c) * 16 + h)) * 4096;
  {
    const int s = tid >> 2, e0 = (tid & 3) * 16;
    const unsigned short* gq = Qb + gbase + (size_t)s * 1024 + e0;
    const unsigned short* gk = Kb + gbase + (size_t)s * 1024 + e0;
    const unsigned short* gx = Xb + gbase + (size_t)s * 1024 + e0;
    const unsigned short* gs = Sg + sbase + (size_t)s * 64 + e0;
    *(u32x4*)&Cb[s * 72 + e0] = *(const u32x4*)gq;
    *(u32x4*)&Cb[s * 72 + e0 + 8] = *(const u32x4*)(gq + 8);
    *(u32x4*)&Bb[s * 72 + e0] = *(const u32x4*)gk;
    *(u32x4*)&Bb[s * 72 + e0 + 8] = *(const u32x4*)(gk + 8);
    *(u32x4*)&TG[s * 72 + e0] = *(const u32x4*)gx;
    *(u32x4*)&TG[s * 72 + e0 + 8] = *(const u32x4*)(gx + 8);
    *(u32x4*)&Sb[s * 72 + e0] = *(const u32x4*)gs;
    *(u32x4*)&Sb[s * 72 + e0 + 8] = *(const u32x4*)(gs + 8);
  }
  if (w == 0) {
    float a = -expf(A_log[h]) * dtb[((size_t)(b * 4096 + c * 64 + lane)) * 16 + h];
    float v = a;
#pragma unroll
    for (int d = 1; d < 64; d <<= 1) {
      float o = __shfl_up(v, d, 64);
      if (lane >= d) v += o;
    }
    csL[lane] = v;
    sdeL[lane] = expf(v);
  }
  __syncthreads();
  const int lr = lane & 15, lk = (lane >> 4) * 8;
  // G = C @ B^T (contract n)
  f32x4 g[4] = {};
#pragma unroll
  for (int kt = 0; kt < 64; kt += 32) {
    bf16x8 aF = *reinterpret_cast<const bf16x8*>(&Cb[(w * 16 + lr) * 72 + kt + lk]);
#pragma unroll
    for (int j = 0; j < 4; ++j) {
      bf16x8 bF = *reinterpret_cast<const bf16x8*>(&Bb[(j * 16 + lr) * 72 + kt + lk]);
      g[j] = __builtin_amdgcn_mfma_f32_16x16x32_bf16(aF, bF, g[j], 0, 0, 0);
    }
  }
  // transpose X: TG -> Xt
#pragma unroll
  for (int q = 0; q < 2; ++q) {
    const int p = lane;
    const int s0 = (q * 4 + w) * 8;
    u16x8 vx;
#pragma unroll
    for (int j = 0; j < 8; ++j) vx[j] = TG[(s0 + j) * 72 + p];
    *(u16x8*)&Xt[p * 72 + s0] = vx;
  }
  __syncthreads();
  // Gm = (G o L) -> TG ;  Cb *= sde[l]
#pragma unroll
  for (int j = 0; j < 4; ++j)
#pragma unroll
    for (int r = 0; r < 4; ++r) {
      const int l = w * 16 + (lane >> 4) * 4 + r;
      const int s = j * 16 + lr;
      const float gm = (l >= s) ? g[j][r] * expf(csL[l] - csL[s]) : 0.f;
      TG[l * 72 + s] = f2bf(gm);
    }
  {
    const int rl = tid >> 2, e0 = (tid & 3) * 16;
    const float sde = sdeL[rl];
#pragma unroll
    for (int half = 0; half < 2; ++half) {
      u16x8 v = *(u16x8*)&Cb[rl * 72 + e0 + half * 8];
#pragma unroll
      for (int j = 0; j < 8; ++j) v[j] = f2bf(bf2f(v[j]) * sde);
      *(u16x8*)&Cb[rl * 72 + e0 + half * 8] = v;
    }
  }
  __syncthreads();
  // Y = Gm @ Xt^T + Csde @ S^T
  f32x4 acc[4] = {};
#pragma unroll
  for (int kt = 0; kt < 64; kt += 32) {
    bf16x8 aG = *reinterpret_cast<const bf16x8*>(&TG[(w * 16 + lr) * 72 + kt + lk]);
    bf16x8 aC = *reinterpret_cast<const bf16x8*>(&Cb[(w * 16 + lr) * 72 + kt + lk]);
#pragma unroll
    for (int j = 0; j < 4; ++j) {
      bf16x8 bX = *reinterpret_cast<const bf16x8*>(&Xt[(j * 16 + lr) * 72 + kt + lk]);
      bf16x8 bS = *reinterpret_cast<const bf16x8*>(&Sb[(j * 16 + lr) * 72 + kt + lk]);
      acc[j] = __builtin_amdgcn_mfma_f32_16x16x32_bf16(aG, bX, acc[j], 0, 0, 0);
      acc[j] = __builtin_amdgcn_mfma_f32_16x16x32_bf16(aC, bS, acc[j], 0, 0, 0);
    }
  }
  // scrambled store: row = b*4096 + h*256 + c*4 + (l>>4), col = (l&15)*64 + p
  const size_t orow = (size_t)b * 4096 + h * 256 + c * 4 + w;
#pragma unroll
  for (int j = 0; j < 4; ++j)
#pragma unroll
    for (int r = 0; r < 4; ++r) {
      const int li = (lane >> 4) * 4 + r;
      y_bf[orow * 1024 + li * 64 + j * 16 + lr] = f2bf(acc[j][r]);
    }
}

// ---------------------------------------------------------------------------
extern "C" void kernel_launch(void* const* d_in, const int* in_sizes, int n_in,
                              void* d_out, int out_size, void* d_ws, size_t ws_size,
                              hipStream_t stream) {
  (void)in_sizes; (void)n_in; (void)out_size; (void)ws_size;
  const float* x = (const float*)d_in[0];
  const float* cosb = (const float*)d_in[1];
  const float* sinb = (const float*)d_in[2];
  const float* wq = (const float*)d_in[3];
  const float* wk = (const float*)d_in[4];
  const float* wv = (const float*)d_in[5];
  const float* wo = (const float*)d_in[6];
  const float* A_log = (const float*)d_in[7];
  const float* wdt = (const float*)d_in[8];
  const float* bdt = (const float*)d_in[9];

  float* out_y = (float*)d_out;        // (2,4096,1024) f32
  float* out_state = out_y + 8388608;  // (2,16,64,64) f32

  const size_t MBB = 1048576;
  char* ws = (char*)d_ws;
  unsigned short* x_bf = (unsigned short*)(ws);              // 16MB, reused as y_bf
  unsigned short* w_t = (unsigned short*)(ws + 16 * MBB);    // 8MB
  unsigned short* q_bf = (unsigned short*)(ws + 24 * MBB);   // 16MB
  unsigned short* k_bf = (unsigned short*)(ws + 40 * MBB);   // 16MB
  unsigned short* xv_bf = (unsigned short*)(ws + 56 * MBB);  // 16MB
  float* dtb = (float*)(ws + 72 * MBB);                      // 0.5MB
  unsigned short* wdt_bf = (unsigned short*)(ws + 73 * MBB); // 32KB
  unsigned short* chunk_states = (unsigned short*)(ws + 74 * MBB);  // 16MB bf16
  float* chunk_dec = (float*)(ws + 90 * MBB);                // 8KB
  unsigned short* inc_bf = (unsigned short*)(ws + 91 * MBB); // 16MB

  convert_bf16_kernel<<<8192, 256, 0, stream>>>(x, x_bf, 2097152);
  transpose_w_kernel<<<dim3(32, 32, 4), dim3(32, 8), 0, stream>>>(wq, wk, wv, wo, w_t);
  wdt_t_kernel<<<64, 256, 0, stream>>>(wdt, wdt_bf);
  dt_gemm_kernel<<<128, 256, 0, stream>>>(x_bf, wdt_bf, bdt, dtb);

  dim3 ggrid(8, 64);  // N/128, M/128
  gemm128_kernel<1><<<ggrid, 256, 0, stream>>>(x_bf, w_t + 0 * MBB, q_bf, cosb, sinb, nullptr);
  gemm128_kernel<1><<<ggrid, 256, 0, stream>>>(x_bf, w_t + 1 * MBB, k_bf, cosb, sinb, nullptr);
  gemm128_kernel<2><<<ggrid, 256, 0, stream>>>(x_bf, w_t + 2 * MBB, xv_bf, nullptr, nullptr, dtb);

  ssd_states_kernel<<<dim3(64, 16, 2), 256, 0, stream>>>(k_bf, xv_bf, dtb, A_log,
                                                         chunk_states, chunk_dec);
  scan_kernel<<<512, 256, 0, stream>>>(chunk_states, chunk_dec, inc_bf, out_state);
  ssd_y_kernel<<<dim3(64, 16, 2), 256, 0, stream>>>(q_bf, k_bf, xv_bf, inc_bf, dtb, A_log,
                                                    x_bf /*y_bf*/);

  gemm128_kernel<0><<<ggrid, 256, 0, stream>>>(x_bf /*y_bf*/, w_t + 3 * MBB, out_y,
                                               nullptr, nullptr, nullptr);
}

// Round 4
// 180.062 us; speedup vs baseline: 1.8287x; 1.0625x over previous
//
#include <hip/hip_runtime.h>

// ---------------------------------------------------------------------------
// Mamba-2 block (BATCH=2, SEQ=4096, DIM=1024, NH=16, HD=64, BLOCK=64)
//   1) convert: x -> bf16 (+ tail blocks: wdt -> bf16 16x1024)
//   2) transpose wq/wk/wv/wo -> bf16 (N x K), contiguous (N=4096 total)
//   3) dt = softplus(x_bf @ wdt^T + b)  [MFMA]
//   4) ONE fused QKV GEMM (N=3072) with per-column-block epilogues:
//        q_bf / k_bf = RoPE(x@w) bf16 ; xv_bf = (x@wv)*dt bf16
//   5) ssd_states (MFMA): chunk states (bf16) + chunk decay
//   6) scan (prefetch-pipelined): inc states (bf16) + final state -> d_out tail
//   7) ssd_y (MFMA): Y = (C@B^T . L)@X + (C.sde)@S^T, scrambled bf16 y
//   8) GEMM: out = y @ wo (f32 -> d_out)
// ---------------------------------------------------------------------------

typedef __bf16 bf16x8 __attribute__((ext_vector_type(8)));
typedef float f32x4 __attribute__((ext_vector_type(4)));
typedef unsigned int u32x4 __attribute__((ext_vector_type(4)));
typedef unsigned short u16x8 __attribute__((ext_vector_type(8)));
typedef unsigned short u16x4 __attribute__((ext_vector_type(4)));

__device__ __forceinline__ unsigned short f2bf(float f) {
  unsigned int u = __builtin_bit_cast(unsigned int, f);
  u += 0x7fffu + ((u >> 16) & 1u);  // RNE
  return (unsigned short)(u >> 16);
}
__device__ __forceinline__ float bf2f(unsigned short s) {
  unsigned int u = ((unsigned int)s) << 16;
  return __builtin_bit_cast(float, u);
}

#define GLOAD16(gp, lp)                                                \
  __builtin_amdgcn_global_load_lds(                                    \
      (const __attribute__((address_space(1))) void*)(gp),             \
      (__attribute__((address_space(3))) void*)(lp), 16, 0, 0)

// ---------------- convert x -> bf16 ; tail blocks: wdt -> (16,1024) bf16 ----
__global__ __launch_bounds__(256) void convert_bf16_kernel(
    const float* __restrict__ in, unsigned short* __restrict__ out, int n4,
    const float* __restrict__ wdt, unsigned short* __restrict__ wdt_bf) {
  const int bx = blockIdx.x;
  if (bx < 8192) {
    int g = bx * 256 + threadIdx.x;
    if (g < n4) {
      f32x4 v = *reinterpret_cast<const f32x4*>(in + (size_t)g * 4);
      u16x4 o;
      o.x = f2bf(v.x); o.y = f2bf(v.y); o.z = f2bf(v.z); o.w = f2bf(v.w);
      *reinterpret_cast<u16x4*>(out + (size_t)g * 4) = o;
    }
  } else {
    const int g = (bx - 8192) * 256 + threadIdx.x;  // 0..16383
    const int n = g >> 10, k = g & 1023;
    wdt_bf[g] = f2bf(wdt[k * 16 + n]);
  }
}

// ---------------- transpose 1024x1024 f32 -> bf16 (N x K), 4 mats ----------------
__global__ __launch_bounds__(256) void transpose_w_kernel(
    const float* __restrict__ w0, const float* __restrict__ w1,
    const float* __restrict__ w2, const float* __restrict__ w3,
    unsigned short* __restrict__ wt) {
  __shared__ float tile[32][33];
  const int z = blockIdx.z;
  const float* w = (z == 0) ? w0 : (z == 1) ? w1 : (z == 2) ? w2 : w3;
  unsigned short* o = wt + (size_t)z * 1024 * 1024;
  const int bx = blockIdx.x, by = blockIdx.y;
  const int tx = threadIdx.x, ty = threadIdx.y;  // (32,8)
#pragma unroll
  for (int i = 0; i < 4; ++i)
    tile[ty + i * 8][tx] = w[(size_t)(by * 32 + ty + i * 8) * 1024 + bx * 32 + tx];
  __syncthreads();
#pragma unroll
  for (int i = 0; i < 4; ++i)
    o[(size_t)(bx * 32 + ty + i * 8) * 1024 + by * 32 + tx] = f2bf(tile[tx][ty + i * 8]);
}

// ---------------- dt = softplus(x_bf @ wdt_t^T + b)  [MFMA] ----------------
__global__ __launch_bounds__(256) void dt_gemm_kernel(
    const unsigned short* __restrict__ A,   // 8192x1024 bf16
    const unsigned short* __restrict__ Bt,  // 16x1024 bf16
    const float* __restrict__ bdt, float* __restrict__ dt) {
  __shared__ unsigned short As[2 * 64 * 32];  // [kk][64][32]
  const int tid = threadIdx.x, lane = tid & 63, w = tid >> 6;
  const int m0 = blockIdx.x * 64;
  const unsigned short* ga =
      A + (size_t)(m0 + w * 16 + (lane >> 2)) * 1024 + (lane & 3) * 8;
  unsigned short* la = As + w * 512;  // wave-uniform base (elements)
  const int lr = lane & 15, lk = (lane >> 4) * 8;
  const unsigned short* gb = Bt + (size_t)lr * 1024 + lk;
  f32x4 acc = {};
  for (int kt = 0; kt < 1024; kt += 64) {
    GLOAD16(ga + kt, la);                 // k-half 0
    GLOAD16(ga + kt + 32, la + 2048);     // k-half 1
    bf16x8 bF0 = *reinterpret_cast<const bf16x8*>(gb + kt);
    bf16x8 bF1 = *reinterpret_cast<const bf16x8*>(gb + kt + 32);
    __syncthreads();
    bf16x8 aF0 = *reinterpret_cast<const bf16x8*>(&As[(w * 16 + lr) * 32 + lk]);
    bf16x8 aF1 = *reinterpret_cast<const bf16x8*>(&As[2048 + (w * 16 + lr) * 32 + lk]);
    acc = __builtin_amdgcn_mfma_f32_16x16x32_bf16(aF0, bF0, acc, 0, 0, 0);
    acc = __builtin_amdgcn_mfma_f32_16x16x32_bf16(aF1, bF1, acc, 0, 0, 0);
    __syncthreads();
  }
  const int h = lr;  // C/D: col = lane&15
  const float bv = bdt[h];
#pragma unroll
  for (int r = 0; r < 4; ++r) {
    const int row = m0 + w * 16 + (lane >> 4) * 4 + r;
    const float a = acc[r] + bv;
    const float sp = (a > 0.f) ? (a + log1pf(expf(-a))) : log1pf(expf(a));
    dt[(size_t)row * 16 + h] = sp;
  }
}

// ---------------- m97-style bf16 GEMM ----------------
// EPI 0: plain f32 out (out = y @ wo).  EPI 3: fused QKV epilogue.
template <int EPI>
__global__ __launch_bounds__(256) void gemm128_kernel(
    const unsigned short* __restrict__ A, const unsigned short* __restrict__ Bt,
    void* __restrict__ out0, unsigned short* __restrict__ out1,
    unsigned short* __restrict__ out2, const float* __restrict__ cosb,
    const float* __restrict__ sinb, const float* __restrict__ dtb) {
  __shared__ unsigned short As[128 * 32];
  __shared__ unsigned short Bs[128 * 32];
  const int tid = threadIdx.x, lane = tid & 63, w = tid >> 6;
  const int m0 = blockIdx.y * 128, n0 = blockIdx.x * 128;
  const int srow = w * 32 + (lane >> 2);
  const int scol = (lane & 3) * 8;
  const unsigned short* ga = A + (size_t)(m0 + srow) * 1024 + scol;
  const unsigned short* gb = Bt + (size_t)(n0 + srow) * 1024 + scol;
  unsigned short* la = As + (w * 32) * 32;  // wave-uniform LDS base
  unsigned short* lb = Bs + (w * 32) * 32;
  const int lr = lane & 15, lk = (lane >> 4) * 8;
  const int wr = w >> 1, wc = w & 1;
  f32x4 acc[4][4] = {};
  for (int kt = 0; kt < 1024; kt += 32) {
    GLOAD16(ga + kt, la);
    GLOAD16(ga + kt + (size_t)16 * 1024, la + 16 * 32);
    GLOAD16(gb + kt, lb);
    GLOAD16(gb + kt + (size_t)16 * 1024, lb + 16 * 32);
    __syncthreads();
    bf16x8 aF[4], bF[4];
#pragma unroll
    for (int i = 0; i < 4; ++i) {
      aF[i] = *reinterpret_cast<const bf16x8*>(&As[(wr * 64 + i * 16 + lr) * 32 + lk]);
      bF[i] = *reinterpret_cast<const bf16x8*>(&Bs[(wc * 64 + i * 16 + lr) * 32 + lk]);
    }
#pragma unroll
    for (int i = 0; i < 4; ++i)
#pragma unroll
      for (int j = 0; j < 4; ++j)
        acc[i][j] = __builtin_amdgcn_mfma_f32_16x16x32_bf16(aF[i], bF[j], acc[i][j], 0, 0, 0);
    __syncthreads();
  }
  const int r0 = m0 + wr * 64 + ((lane >> 4) << 2);
  if constexpr (EPI == 0) {
    float* O = (float*)out0;
    const int c0 = n0 + wc * 64 + lr;
#pragma unroll
    for (int i = 0; i < 4; ++i)
#pragma unroll
      for (int j = 0; j < 4; ++j)
#pragma unroll
        for (int r = 0; r < 4; ++r)
          O[(size_t)(r0 + i * 16 + r) * 1024 + c0 + j * 16] = acc[i][j][r];
  } else {
    const int col = n0 + wc * 64;  // 64-aligned, 0..3008
    if (col < 2048) {
      // RoPE epilogue -> q_bf (out0) or k_bf (out1)
      unsigned short* O = (col < 1024) ? (unsigned short*)out0 : out1;
      const int cbase = col & 1023;
#pragma unroll
      for (int i = 0; i < 4; ++i)
#pragma unroll
        for (int jj = 0; jj < 2; ++jj) {
          const int d1 = jj * 16 + lr;  // 0..31; cos[d]==cos[d+32]
#pragma unroll
          for (int r = 0; r < 4; ++r) {
            const int row = r0 + i * 16 + r;
            const int l = row & 4095;
            const float cv = cosb[(size_t)l * 64 + d1];
            const float sv = sinb[(size_t)l * 64 + d1];
            const float v1 = acc[i][jj][r], v2 = acc[i][jj + 2][r];
            O[(size_t)row * 1024 + cbase + jj * 16 + lr] = f2bf(v1 * cv - v2 * sv);
            O[(size_t)row * 1024 + cbase + jj * 16 + lr + 32] = f2bf(v2 * cv + v1 * sv);
          }
        }
    } else {
      // dt-scale epilogue -> xv_bf (out2)
      unsigned short* O = out2;
      const int cbase = col - 2048;
      const int h = cbase >> 6;
#pragma unroll
      for (int i = 0; i < 4; ++i)
#pragma unroll
        for (int r = 0; r < 4; ++r) {
          const int row = r0 + i * 16 + r;
          const float dtv = dtb[(size_t)row * 16 + h];
#pragma unroll
          for (int j = 0; j < 4; ++j)
            O[(size_t)row * 1024 + cbase + j * 16 + lr] = f2bf(acc[i][j][r] * dtv);
        }
    }
  }
}

// ---------------- SSD pre-scan: chunk states (MFMA, bf16 out) ----------------
__global__ __launch_bounds__(256) void ssd_states_kernel(
    const unsigned short* __restrict__ Kb, const unsigned short* __restrict__ Xb,
    const float* __restrict__ dtb, const float* __restrict__ A_log,
    unsigned short* __restrict__ chunk_states, float* __restrict__ chunk_dec) {
  __shared__ unsigned short T1[64 * 72], T2[64 * 72];   // B, X row-major
  __shared__ unsigned short BtL[64 * 72], XdL[64 * 72]; // transposed (k = s)
  __shared__ float csL[64], decL[64];
  const int c = blockIdx.x, h = blockIdx.y, b = blockIdx.z;
  const int tid = threadIdx.x, lane = tid & 63, w = tid >> 6;
  const size_t gbase = ((size_t)(b * 4096 + c * 64)) * 1024 + h * 64;
  {
    const int s = tid >> 2, e0 = (tid & 3) * 16;
    const unsigned short* gk = Kb + gbase + (size_t)s * 1024 + e0;
    const unsigned short* gx = Xb + gbase + (size_t)s * 1024 + e0;
    *(u32x4*)&T1[s * 72 + e0] = *(const u32x4*)gk;
    *(u32x4*)&T1[s * 72 + e0 + 8] = *(const u32x4*)(gk + 8);
    *(u32x4*)&T2[s * 72 + e0] = *(const u32x4*)gx;
    *(u32x4*)&T2[s * 72 + e0 + 8] = *(const u32x4*)(gx + 8);
  }
  if (w == 0) {
    float a = -expf(A_log[h]) * dtb[((size_t)(b * 4096 + c * 64 + lane)) * 16 + h];
    float v = a;
#pragma unroll
    for (int d = 1; d < 64; d <<= 1) {
      float o = __shfl_up(v, d, 64);
      if (lane >= d) v += o;
    }
    const float tot = __shfl(v, 63, 64);
    csL[lane] = v;
    decL[lane] = expf(tot - v);
    if (lane == 0) chunk_dec[((size_t)(b * 16 + h)) * 64 + c] = expf(tot);
  }
  __syncthreads();
#pragma unroll
  for (int q = 0; q < 2; ++q) {  // transpose with dec fold-in
    const int p = lane;
    const int s0 = (q * 4 + w) * 8;
    u16x8 vb, vx;
#pragma unroll
    for (int j = 0; j < 8; ++j) {
      vb[j] = T1[(s0 + j) * 72 + p];
      vx[j] = f2bf(bf2f(T2[(s0 + j) * 72 + p]) * decL[s0 + j]);
    }
    *(u16x8*)&BtL[p * 72 + s0] = vb;
    *(u16x8*)&XdL[p * 72 + s0] = vx;
  }
  __syncthreads();
  const int lr = lane & 15, lk = (lane >> 4) * 8;
  f32x4 acc[4] = {};
#pragma unroll
  for (int kt = 0; kt < 64; kt += 32) {
    bf16x8 aF = *reinterpret_cast<const bf16x8*>(&XdL[(w * 16 + lr) * 72 + kt + lk]);
#pragma unroll
    for (int j = 0; j < 4; ++j) {
      bf16x8 bF = *reinterpret_cast<const bf16x8*>(&BtL[(j * 16 + lr) * 72 + kt + lk]);
      acc[j] = __builtin_amdgcn_mfma_f32_16x16x32_bf16(aF, bF, acc[j], 0, 0, 0);
    }
  }
  const size_t stb = ((size_t)((b * 64 + c) * 16 + h)) * 4096;
#pragma unroll
  for (int j = 0; j < 4; ++j)
#pragma unroll
    for (int r = 0; r < 4; ++r)
      chunk_states[stb + (size_t)(w * 16 + (lane >> 4) * 4 + r) * 64 + j * 16 + lr] =
          f2bf(acc[j][r]);
}

// ---------------- inter-chunk scan (prefetch-pipelined) ----------------
__global__ __launch_bounds__(256) void scan_kernel(
    const unsigned short* __restrict__ chunk_states, const float* __restrict__ chunk_dec,
    unsigned short* __restrict__ inc_bf, float* __restrict__ state_out) {
  __shared__ float decs[64];
  const int g = blockIdx.x * 256 + threadIdx.x;
  const int n = g & 63, p = (g >> 6) & 63, h = (g >> 12) & 15, b = g >> 16;
  if (threadIdx.x < 64)
    decs[threadIdx.x] = chunk_dec[(size_t)((blockIdx.x * 256) >> 12 & 15) * 64 +
                                  (size_t)(blockIdx.x >> 8) * 1024 + threadIdx.x];
  __syncthreads();
  const size_t pn = (size_t)p * 64 + n;
  const size_t stride = (size_t)16 * 4096;
  const size_t base0 = ((size_t)(b * 64) * 16 + h) * 4096 + pn;
  float inc = 0.f;
  float cur = bf2f(chunk_states[base0]);
  for (int c = 0; c < 64; ++c) {
    const size_t idx = base0 + (size_t)c * stride;
    inc_bf[idx] = f2bf(inc);
    float nxt = (c < 63) ? bf2f(chunk_states[idx + stride]) : 0.f;
    inc = decs[c] * inc + cur;
    cur = nxt;
  }
  state_out[((size_t)(b * 16 + h) * 64 + p) * 64 + n] = inc;
}

// ---------------- SSD post-scan: Y = Gm@X + (C.sde)@S^T (MFMA) ----------------
__global__ __launch_bounds__(256) void ssd_y_kernel(
    const unsigned short* __restrict__ Qb, const unsigned short* __restrict__ Kb,
    const unsigned short* __restrict__ Xb, const unsigned short* __restrict__ Sg,
    const float* __restrict__ dtb, const float* __restrict__ A_log,
    unsigned short* __restrict__ y_bf) {
  __shared__ unsigned short Cb[64 * 72], Bb[64 * 72], Sb[64 * 72];
  __shared__ unsigned short Xt[64 * 72], TG[64 * 72];  // TG: X rm, then Gm
  __shared__ float csL[64], sdeL[64];
  const int c = blockIdx.x, h = blockIdx.y, b = blockIdx.z;
  const int tid = threadIdx.x, lane = tid & 63, w = tid >> 6;
  const size_t gbase = ((size_t)(b * 4096 + c * 64)) * 1024 + h * 64;
  const size_t sbase = ((size_t)((b * 64 + c) * 16 + h)) * 4096;
  {
    const int s = tid >> 2, e0 = (tid & 3) * 16;
    const unsigned short* gq = Qb + gbase + (size_t)s * 1024 + e0;
    const unsigned short* gk = Kb + gbase + (size_t)s * 1024 + e0;
    const unsigned short* gx = Xb + gbase + (size_t)s * 1024 + e0;
    const unsigned short* gs = Sg + sbase + (size_t)s * 64 + e0;
    *(u32x4*)&Cb[s * 72 + e0] = *(const u32x4*)gq;
    *(u32x4*)&Cb[s * 72 + e0 + 8] = *(const u32x4*)(gq + 8);
    *(u32x4*)&Bb[s * 72 + e0] = *(const u32x4*)gk;
    *(u32x4*)&Bb[s * 72 + e0 + 8] = *(const u32x4*)(gk + 8);
    *(u32x4*)&TG[s * 72 + e0] = *(const u32x4*)gx;
    *(u32x4*)&TG[s * 72 + e0 + 8] = *(const u32x4*)(gx + 8);
    *(u32x4*)&Sb[s * 72 + e0] = *(const u32x4*)gs;
    *(u32x4*)&Sb[s * 72 + e0 + 8] = *(const u32x4*)(gs + 8);
  }
  if (w == 0) {
    float a = -expf(A_log[h]) * dtb[((size_t)(b * 4096 + c * 64 + lane)) * 16 + h];
    float v = a;
#pragma unroll
    for (int d = 1; d < 64; d <<= 1) {
      float o = __shfl_up(v, d, 64);
      if (lane >= d) v += o;
    }
    csL[lane] = v;
    sdeL[lane] = expf(v);
  }
  __syncthreads();
  const int lr = lane & 15, lk = (lane >> 4) * 8;
  // G = C @ B^T (contract n)
  f32x4 g[4] = {};
#pragma unroll
  for (int kt = 0; kt < 64; kt += 32) {
    bf16x8 aF = *reinterpret_cast<const bf16x8*>(&Cb[(w * 16 + lr) * 72 + kt + lk]);
#pragma unroll
    for (int j = 0; j < 4; ++j) {
      bf16x8 bF = *reinterpret_cast<const bf16x8*>(&Bb[(j * 16 + lr) * 72 + kt + lk]);
      g[j] = __builtin_amdgcn_mfma_f32_16x16x32_bf16(aF, bF, g[j], 0, 0, 0);
    }
  }
  // transpose X: TG -> Xt
#pragma unroll
  for (int q = 0; q < 2; ++q) {
    const int p = lane;
    const int s0 = (q * 4 + w) * 8;
    u16x8 vx;
#pragma unroll
    for (int j = 0; j < 8; ++j) vx[j] = TG[(s0 + j) * 72 + p];
    *(u16x8*)&Xt[p * 72 + s0] = vx;
  }
  __syncthreads();
  // Gm = (G o L) -> TG ;  Cb *= sde[l]
#pragma unroll
  for (int j = 0; j < 4; ++j)
#pragma unroll
    for (int r = 0; r < 4; ++r) {
      const int l = w * 16 + (lane >> 4) * 4 + r;
      const int s = j * 16 + lr;
      const float gm = (l >= s) ? g[j][r] * expf(csL[l] - csL[s]) : 0.f;
      TG[l * 72 + s] = f2bf(gm);
    }
  {
    const int rl = tid >> 2, e0 = (tid & 3) * 16;
    const float sde = sdeL[rl];
#pragma unroll
    for (int half = 0; half < 2; ++half) {
      u16x8 v = *(u16x8*)&Cb[rl * 72 + e0 + half * 8];
#pragma unroll
      for (int j = 0; j < 8; ++j) v[j] = f2bf(bf2f(v[j]) * sde);
      *(u16x8*)&Cb[rl * 72 + e0 + half * 8] = v;
    }
  }
  __syncthreads();
  // Y = Gm @ Xt^T + Csde @ S^T
  f32x4 acc[4] = {};
#pragma unroll
  for (int kt = 0; kt < 64; kt += 32) {
    bf16x8 aG = *reinterpret_cast<const bf16x8*>(&TG[(w * 16 + lr) * 72 + kt + lk]);
    bf16x8 aC = *reinterpret_cast<const bf16x8*>(&Cb[(w * 16 + lr) * 72 + kt + lk]);
#pragma unroll
    for (int j = 0; j < 4; ++j) {
      bf16x8 bX = *reinterpret_cast<const bf16x8*>(&Xt[(j * 16 + lr) * 72 + kt + lk]);
      bf16x8 bS = *reinterpret_cast<const bf16x8*>(&Sb[(j * 16 + lr) * 72 + kt + lk]);
      acc[j] = __builtin_amdgcn_mfma_f32_16x16x32_bf16(aG, bX, acc[j], 0, 0, 0);
      acc[j] = __builtin_amdgcn_mfma_f32_16x16x32_bf16(aC, bS, acc[j], 0, 0, 0);
    }
  }
  // scrambled store: row = b*4096 + h*256 + c*4 + (l>>4), col = (l&15)*64 + p
  const size_t orow = (size_t)b * 4096 + h * 256 + c * 4 + w;
#pragma unroll
  for (int j = 0; j < 4; ++j)
#pragma unroll
    for (int r = 0; r < 4; ++r) {
      const int li = (lane >> 4) * 4 + r;
      y_bf[orow * 1024 + li * 64 + j * 16 + lr] = f2bf(acc[j][r]);
    }
}

// ---------------------------------------------------------------------------
extern "C" void kernel_launch(void* const* d_in, const int* in_sizes, int n_in,
                              void* d_out, int out_size, void* d_ws, size_t ws_size,
                              hipStream_t stream) {
  (void)in_sizes; (void)n_in; (void)out_size; (void)ws_size;
  const float* x = (const float*)d_in[0];
  const float* cosb = (const float*)d_in[1];
  const float* sinb = (const float*)d_in[2];
  const float* wq = (const float*)d_in[3];
  const float* wk = (const float*)d_in[4];
  const float* wv = (const float*)d_in[5];
  const float* wo = (const float*)d_in[6];
  const float* A_log = (const float*)d_in[7];
  const float* wdt = (const float*)d_in[8];
  const float* bdt = (const float*)d_in[9];

  float* out_y = (float*)d_out;        // (2,4096,1024) f32
  float* out_state = out_y + 8388608;  // (2,16,64,64) f32

  const size_t MBB = 1048576;
  char* ws = (char*)d_ws;
  unsigned short* x_bf = (unsigned short*)(ws);              // 16MB, reused as y_bf
  unsigned short* w_t = (unsigned short*)(ws + 16 * MBB);    // 8MB (q,k,v,o transposed)
  unsigned short* q_bf = (unsigned short*)(ws + 24 * MBB);   // 16MB
  unsigned short* k_bf = (unsigned short*)(ws + 40 * MBB);   // 16MB
  unsigned short* xv_bf = (unsigned short*)(ws + 56 * MBB);  // 16MB
  float* dtb = (float*)(ws + 72 * MBB);                      // 0.5MB
  unsigned short* wdt_bf = (unsigned short*)(ws + 73 * MBB); // 32KB
  unsigned short* chunk_states = (unsigned short*)(ws + 74 * MBB);  // 16MB bf16
  float* chunk_dec = (float*)(ws + 90 * MBB);                // 8KB
  unsigned short* inc_bf = (unsigned short*)(ws + 91 * MBB); // 16MB

  convert_bf16_kernel<<<8256, 256, 0, stream>>>(x, x_bf, 2097152, wdt, wdt_bf);
  transpose_w_kernel<<<dim3(32, 32, 4), dim3(32, 8), 0, stream>>>(wq, wk, wv, wo, w_t);
  dt_gemm_kernel<<<128, 256, 0, stream>>>(x_bf, wdt_bf, bdt, dtb);

  // fused QKV GEMM: N = 3072 (wq^T | wk^T | wv^T contiguous in w_t)
  gemm128_kernel<3><<<dim3(24, 64), 256, 0, stream>>>(
      x_bf, w_t, q_bf, k_bf, xv_bf, cosb, sinb, dtb);

  ssd_states_kernel<<<dim3(64, 16, 2), 256, 0, stream>>>(k_bf, xv_bf, dtb, A_log,
                                                         chunk_states, chunk_dec);
  scan_kernel<<<512, 256, 0, stream>>>(chunk_states, chunk_dec, inc_bf, out_state);
  ssd_y_kernel<<<dim3(64, 16, 2), 256, 0, stream>>>(q_bf, k_bf, xv_bf, inc_bf, dtb, A_log,
                                                    x_bf /*y_bf*/);

  gemm128_kernel<0><<<dim3(8, 64), 256, 0, stream>>>(
      x_bf /*y_bf*/, w_t + 3 * MBB, out_y, nullptr, nullptr, nullptr, nullptr, nullptr);
}

// Round 5
// 162.426 us; speedup vs baseline: 2.0273x; 1.1086x over previous
//
#include <hip/hip_runtime.h>

// ---------------------------------------------------------------------------
// Mamba-2 block (BATCH=2, SEQ=4096, DIM=1024, NH=16, HD=64, BLOCK=64)
//   1) convert: x -> bf16 (+ tail blocks: wdt -> bf16 16x1024)
//   2) transpose wq/wk/wv/wo -> bf16 (N x K), contiguous
//   3) dt = softplus(x_bf @ wdt^T + b)  [MFMA]
//   4) ONE fused QKV GEMM (N=3072), BK=64 XOR-swizzled LDS, epilogues:
//        q_bf / k_bf = RoPE(x@w) bf16 ; xv_bf = (x@wv)*dt bf16
//   5) ssd_states (MFMA): chunk states (bf16) + chunk decay
//   6) scan (prefetch-pipelined): inc states (bf16) + final state -> d_out tail
//   7) ssd_y (MFMA): Y = (C@B^T . L)@X + (C.sde)@S^T, scrambled bf16 y
//   8) GEMM: out = y @ wo (f32 -> d_out), same BK=64 structure
// ---------------------------------------------------------------------------

typedef __bf16 bf16x8 __attribute__((ext_vector_type(8)));
typedef float f32x4 __attribute__((ext_vector_type(4)));
typedef unsigned int u32x4 __attribute__((ext_vector_type(4)));
typedef unsigned short u16x8 __attribute__((ext_vector_type(8)));
typedef unsigned short u16x4 __attribute__((ext_vector_type(4)));

__device__ __forceinline__ unsigned short f2bf(float f) {
  unsigned int u = __builtin_bit_cast(unsigned int, f);
  u += 0x7fffu + ((u >> 16) & 1u);  // RNE
  return (unsigned short)(u >> 16);
}
__device__ __forceinline__ float bf2f(unsigned short s) {
  unsigned int u = ((unsigned int)s) << 16;
  return __builtin_bit_cast(float, u);
}

#define GLOAD16(gp, lp)                                                \
  __builtin_amdgcn_global_load_lds(                                    \
      (const __attribute__((address_space(1))) void*)(gp),             \
      (__attribute__((address_space(3))) void*)(lp), 16, 0, 0)

// ---------------- convert x -> bf16 ; tail blocks: wdt -> (16,1024) bf16 ----
__global__ __launch_bounds__(256) void convert_bf16_kernel(
    const float* __restrict__ in, unsigned short* __restrict__ out, int n4,
    const float* __restrict__ wdt, unsigned short* __restrict__ wdt_bf) {
  const int bx = blockIdx.x;
  if (bx < 8192) {
    int g = bx * 256 + threadIdx.x;
    if (g < n4) {
      f32x4 v = *reinterpret_cast<const f32x4*>(in + (size_t)g * 4);
      u16x4 o;
      o.x = f2bf(v.x); o.y = f2bf(v.y); o.z = f2bf(v.z); o.w = f2bf(v.w);
      *reinterpret_cast<u16x4*>(out + (size_t)g * 4) = o;
    }
  } else {
    const int g = (bx - 8192) * 256 + threadIdx.x;  // 0..16383
    const int n = g >> 10, k = g & 1023;
    wdt_bf[g] = f2bf(wdt[k * 16 + n]);
  }
}

// ---------------- transpose 1024x1024 f32 -> bf16 (N x K), 4 mats ----------------
__global__ __launch_bounds__(256) void transpose_w_kernel(
    const float* __restrict__ w0, const float* __restrict__ w1,
    const float* __restrict__ w2, const float* __restrict__ w3,
    unsigned short* __restrict__ wt) {
  __shared__ float tile[32][33];
  const int z = blockIdx.z;
  const float* w = (z == 0) ? w0 : (z == 1) ? w1 : (z == 2) ? w2 : w3;
  unsigned short* o = wt + (size_t)z * 1024 * 1024;
  const int bx = blockIdx.x, by = blockIdx.y;
  const int tx = threadIdx.x, ty = threadIdx.y;  // (32,8)
#pragma unroll
  for (int i = 0; i < 4; ++i)
    tile[ty + i * 8][tx] = w[(size_t)(by * 32 + ty + i * 8) * 1024 + bx * 32 + tx];
  __syncthreads();
#pragma unroll
  for (int i = 0; i < 4; ++i)
    o[(size_t)(bx * 32 + ty + i * 8) * 1024 + by * 32 + tx] = f2bf(tile[tx][ty + i * 8]);
}

// ---------------- dt = softplus(x_bf @ wdt_t^T + b)  [MFMA] ----------------
__global__ __launch_bounds__(256) void dt_gemm_kernel(
    const unsigned short* __restrict__ A,   // 8192x1024 bf16
    const unsigned short* __restrict__ Bt,  // 16x1024 bf16
    const float* __restrict__ bdt, float* __restrict__ dt) {
  __shared__ unsigned short As[2 * 64 * 32];  // [kk][64][32]
  const int tid = threadIdx.x, lane = tid & 63, w = tid >> 6;
  const int m0 = blockIdx.x * 64;
  const unsigned short* ga =
      A + (size_t)(m0 + w * 16 + (lane >> 2)) * 1024 + (lane & 3) * 8;
  unsigned short* la = As + w * 512;  // wave-uniform base (elements)
  const int lr = lane & 15, lk = (lane >> 4) * 8;
  const unsigned short* gb = Bt + (size_t)lr * 1024 + lk;
  f32x4 acc = {};
  for (int kt = 0; kt < 1024; kt += 64) {
    GLOAD16(ga + kt, la);                 // k-half 0
    GLOAD16(ga + kt + 32, la + 2048);     // k-half 1
    bf16x8 bF0 = *reinterpret_cast<const bf16x8*>(gb + kt);
    bf16x8 bF1 = *reinterpret_cast<const bf16x8*>(gb + kt + 32);
    __syncthreads();
    bf16x8 aF0 = *reinterpret_cast<const bf16x8*>(&As[(w * 16 + lr) * 32 + lk]);
    bf16x8 aF1 = *reinterpret_cast<const bf16x8*>(&As[2048 + (w * 16 + lr) * 32 + lk]);
    acc = __builtin_amdgcn_mfma_f32_16x16x32_bf16(aF0, bF0, acc, 0, 0, 0);
    acc = __builtin_amdgcn_mfma_f32_16x16x32_bf16(aF1, bF1, acc, 0, 0, 0);
    __syncthreads();
  }
  const int h = lr;  // C/D: col = lane&15
  const float bv = bdt[h];
#pragma unroll
  for (int r = 0; r < 4; ++r) {
    const int row = m0 + w * 16 + (lane >> 4) * 4 + r;
    const float a = acc[r] + bv;
    const float sp = (a > 0.f) ? (a + log1pf(expf(-a))) : log1pf(expf(a));
    dt[(size_t)row * 16 + h] = sp;
  }
}

// ---------------- BK=64 XOR-swizzled bf16 GEMM ----------------
// LDS tile [128][64] bf16 (128B rows). Swizzle: LDS(r,u) holds global(r, u^(r&7)),
// u = 16B unit (8 bf16). global_load_lds stays linear-dest; global src col-unit
// is pre-XOR'd; ds_read applies the same XOR. 2-way bank alias only (free).
// EPI 0: plain f32 out (out = y @ wo).  EPI 3: fused QKV epilogue.
template <int EPI>
__global__ __launch_bounds__(256) void gemm128_kernel(
    const unsigned short* __restrict__ A, const unsigned short* __restrict__ Bt,
    void* __restrict__ out0, unsigned short* __restrict__ out1,
    unsigned short* __restrict__ out2, const float* __restrict__ cosb,
    const float* __restrict__ sinb, const float* __restrict__ dtb) {
  __shared__ unsigned short As[128 * 64];
  __shared__ unsigned short Bs[128 * 64];
  const int tid = threadIdx.x, lane = tid & 63, w = tid >> 6;
  const int m0 = blockIdx.y * 128, n0 = blockIdx.x * 128;
  // staging: wave w, GLOAD g stages rows g*32 + w*8 + (lane>>3); src unit pre-swizzled
  const int rw = lane >> 3;                      // row & 7
  const int cu = ((lane & 7) ^ rw) * 8;          // swizzled source col (elements)
  const unsigned short* ga = A + (size_t)(m0 + w * 8 + rw) * 1024 + cu;
  const unsigned short* gb = Bt + (size_t)(n0 + w * 8 + rw) * 1024 + cu;
  unsigned short* la = As + (w * 8) * 64;        // wave-uniform LDS base
  unsigned short* lb = Bs + (w * 8) * 64;
  const int lr = lane & 15, lku = lane >> 4;     // k-unit base 0..3
  const int wr = w >> 1, wc = w & 1;
  const int xr = lr & 7;                         // row&7 for fragment rows
  f32x4 acc[4][4] = {};
  for (int kt = 0; kt < 1024; kt += 64) {
#pragma unroll
    for (int g = 0; g < 4; ++g) {
      GLOAD16(ga + kt + (size_t)(g * 32) * 1024, la + g * 32 * 64);
      GLOAD16(gb + kt + (size_t)(g * 32) * 1024, lb + g * 32 * 64);
    }
    __syncthreads();
#pragma unroll
    for (int kk = 0; kk < 2; ++kk) {  // k-halves of 32
      const int un = (kk * 4 + lku) ^ xr;  // swizzled 16B unit
      bf16x8 aF[4], bF[4];
#pragma unroll
      for (int i = 0; i < 4; ++i) {
        aF[i] = *reinterpret_cast<const bf16x8*>(&As[(wr * 64 + i * 16 + lr) * 64 + un * 8]);
        bF[i] = *reinterpret_cast<const bf16x8*>(&Bs[(wc * 64 + i * 16 + lr) * 64 + un * 8]);
      }
#pragma unroll
      for (int i = 0; i < 4; ++i)
#pragma unroll
        for (int j = 0; j < 4; ++j)
          acc[i][j] = __builtin_amdgcn_mfma_f32_16x16x32_bf16(aF[i], bF[j], acc[i][j], 0, 0, 0);
    }
    __syncthreads();
  }
  const int r0 = m0 + wr * 64 + ((lane >> 4) << 2);
  if constexpr (EPI == 0) {
    float* O = (float*)out0;
    const int c0 = n0 + wc * 64 + lr;
#pragma unroll
    for (int i = 0; i < 4; ++i)
#pragma unroll
      for (int j = 0; j < 4; ++j)
#pragma unroll
        for (int r = 0; r < 4; ++r)
          O[(size_t)(r0 + i * 16 + r) * 1024 + c0 + j * 16] = acc[i][j][r];
  } else {
    const int col = n0 + wc * 64;  // 64-aligned, 0..3008
    if (col < 2048) {
      // RoPE epilogue -> q_bf (out0) or k_bf (out1)
      unsigned short* O = (col < 1024) ? (unsigned short*)out0 : out1;
      const int cbase = col & 1023;
#pragma unroll
      for (int i = 0; i < 4; ++i)
#pragma unroll
        for (int jj = 0; jj < 2; ++jj) {
          const int d1 = jj * 16 + lr;  // 0..31; cos[d]==cos[d+32]
#pragma unroll
          for (int r = 0; r < 4; ++r) {
            const int row = r0 + i * 16 + r;
            const int l = row & 4095;
            const float cv = cosb[(size_t)l * 64 + d1];
            const float sv = sinb[(size_t)l * 64 + d1];
            const float v1 = acc[i][jj][r], v2 = acc[i][jj + 2][r];
            O[(size_t)row * 1024 + cbase + jj * 16 + lr] = f2bf(v1 * cv - v2 * sv);
            O[(size_t)row * 1024 + cbase + jj * 16 + lr + 32] = f2bf(v2 * cv + v1 * sv);
          }
        }
    } else {
      // dt-scale epilogue -> xv_bf (out2)
      unsigned short* O = out2;
      const int cbase = col - 2048;
      const int h = cbase >> 6;
#pragma unroll
      for (int i = 0; i < 4; ++i)
#pragma unroll
        for (int r = 0; r < 4; ++r) {
          const int row = r0 + i * 16 + r;
          const float dtv = dtb[(size_t)row * 16 + h];
#pragma unroll
          for (int j = 0; j < 4; ++j)
            O[(size_t)row * 1024 + cbase + j * 16 + lr] = f2bf(acc[i][j][r] * dtv);
        }
    }
  }
}

// ---------------- SSD pre-scan: chunk states (MFMA, bf16 out) ----------------
__global__ __launch_bounds__(256) void ssd_states_kernel(
    const unsigned short* __restrict__ Kb, const unsigned short* __restrict__ Xb,
    const float* __restrict__ dtb, const float* __restrict__ A_log,
    unsigned short* __restrict__ chunk_states, float* __restrict__ chunk_dec) {
  __shared__ unsigned short T1[64 * 72], T2[64 * 72];   // B, X row-major
  __shared__ unsigned short BtL[64 * 72], XdL[64 * 72]; // transposed (k = s)
  __shared__ float csL[64], decL[64];
  const int c = blockIdx.x, h = blockIdx.y, b = blockIdx.z;
  const int tid = threadIdx.x, lane = tid & 63, w = tid >> 6;
  const size_t gbase = ((size_t)(b * 4096 + c * 64)) * 1024 + h * 64;
  {
    const int s = tid >> 2, e0 = (tid & 3) * 16;
    const unsigned short* gk = Kb + gbase + (size_t)s * 1024 + e0;
    const unsigned short* gx = Xb + gbase + (size_t)s * 1024 + e0;
    *(u32x4*)&T1[s * 72 + e0] = *(const u32x4*)gk;
    *(u32x4*)&T1[s * 72 + e0 + 8] = *(const u32x4*)(gk + 8);
    *(u32x4*)&T2[s * 72 + e0] = *(const u32x4*)gx;
    *(u32x4*)&T2[s * 72 + e0 + 8] = *(const u32x4*)(gx + 8);
  }
  if (w == 0) {
    float a = -expf(A_log[h]) * dtb[((size_t)(b * 4096 + c * 64 + lane)) * 16 + h];
    float v = a;
#pragma unroll
    for (int d = 1; d < 64; d <<= 1) {
      float o = __shfl_up(v, d, 64);
      if (lane >= d) v += o;
    }
    const float tot = __shfl(v, 63, 64);
    csL[lane] = v;
    decL[lane] = expf(tot - v);
    if (lane == 0) chunk_dec[((size_t)(b * 16 + h)) * 64 + c] = expf(tot);
  }
  __syncthreads();
#pragma unroll
  for (int q = 0; q < 2; ++q) {  // transpose with dec fold-in
    const int p = lane;
    const int s0 = (q * 4 + w) * 8;
    u16x8 vb, vx;
#pragma unroll
    for (int j = 0; j < 8; ++j) {
      vb[j] = T1[(s0 + j) * 72 + p];
      vx[j] = f2bf(bf2f(T2[(s0 + j) * 72 + p]) * decL[s0 + j]);
    }
    *(u16x8*)&BtL[p * 72 + s0] = vb;
    *(u16x8*)&XdL[p * 72 + s0] = vx;
  }
  __syncthreads();
  const int lr = lane & 15, lk = (lane >> 4) * 8;
  f32x4 acc[4] = {};
#pragma unroll
  for (int kt = 0; kt < 64; kt += 32) {
    bf16x8 aF = *reinterpret_cast<const bf16x8*>(&XdL[(w * 16 + lr) * 72 + kt + lk]);
#pragma unroll
    for (int j = 0; j < 4; ++j) {
      bf16x8 bF = *reinterpret_cast<const bf16x8*>(&BtL[(j * 16 + lr) * 72 + kt + lk]);
      acc[j] = __builtin_amdgcn_mfma_f32_16x16x32_bf16(aF, bF, acc[j], 0, 0, 0);
    }
  }
  const size_t stb = ((size_t)((b * 64 + c) * 16 + h)) * 4096;
#pragma unroll
  for (int j = 0; j < 4; ++j)
#pragma unroll
    for (int r = 0; r < 4; ++r)
      chunk_states[stb + (size_t)(w * 16 + (lane >> 4) * 4 + r) * 64 + j * 16 + lr] =
          f2bf(acc[j][r]);
}

// ---------------- inter-chunk scan (prefetch-pipelined) ----------------
__global__ __launch_bounds__(256) void scan_kernel(
    const unsigned short* __restrict__ chunk_states, const float* __restrict__ chunk_dec,
    unsigned short* __restrict__ inc_bf, float* __restrict__ state_out) {
  __shared__ float decs[64];
  const int g = blockIdx.x * 256 + threadIdx.x;
  const int n = g & 63, p = (g >> 6) & 63, h = (g >> 12) & 15, b = g >> 16;
  if (threadIdx.x < 64)
    decs[threadIdx.x] = chunk_dec[(size_t)((blockIdx.x * 256) >> 12 & 15) * 64 +
                                  (size_t)(blockIdx.x >> 8) * 1024 + threadIdx.x];
  __syncthreads();
  const size_t pn = (size_t)p * 64 + n;
  const size_t stride = (size_t)16 * 4096;
  const size_t base0 = ((size_t)(b * 64) * 16 + h) * 4096 + pn;
  float inc = 0.f;
  float cur = bf2f(chunk_states[base0]);
  for (int c = 0; c < 64; ++c) {
    const size_t idx = base0 + (size_t)c * stride;
    inc_bf[idx] = f2bf(inc);
    float nxt = (c < 63) ? bf2f(chunk_states[idx + stride]) : 0.f;
    inc = decs[c] * inc + cur;
    cur = nxt;
  }
  state_out[((size_t)(b * 16 + h) * 64 + p) * 64 + n] = inc;
}

// ---------------- SSD post-scan: Y = Gm@X + (C.sde)@S^T (MFMA) ----------------
__global__ __launch_bounds__(256) void ssd_y_kernel(
    const unsigned short* __restrict__ Qb, const unsigned short* __restrict__ Kb,
    const unsigned short* __restrict__ Xb, const unsigned short* __restrict__ Sg,
    const float* __restrict__ dtb, const float* __restrict__ A_log,
    unsigned short* __restrict__ y_bf) {
  __shared__ unsigned short Cb[64 * 72], Bb[64 * 72], Sb[64 * 72];
  __shared__ unsigned short Xt[64 * 72], TG[64 * 72];  // TG: X rm, then Gm
  __shared__ float csL[64], sdeL[64];
  const int c = blockIdx.x, h = blockIdx.y, b = blockIdx.z;
  const int tid = threadIdx.x, lane = tid & 63, w = tid >> 6;
  const size_t gbase = ((size_t)(b * 4096 + c * 64)) * 1024 + h * 64;
  const size_t sbase = ((size_t)((b * 64 + c) * 16 + h)) * 4096;
  {
    const int s = tid >> 2, e0 = (tid & 3) * 16;
    const unsigned short* gq = Qb + gbase + (size_t)s * 1024 + e0;
    const unsigned short* gk = Kb + gbase + (size_t)s * 1024 + e0;
    const unsigned short* gx = Xb + gbase + (size_t)s * 1024 + e0;
    const unsigned short* gs = Sg + sbase + (size_t)s * 64 + e0;
    *(u32x4*)&Cb[s * 72 + e0] = *(const u32x4*)gq;
    *(u32x4*)&Cb[s * 72 + e0 + 8] = *(const u32x4*)(gq + 8);
    *(u32x4*)&Bb[s * 72 + e0] = *(const u32x4*)gk;
    *(u32x4*)&Bb[s * 72 + e0 + 8] = *(const u32x4*)(gk + 8);
    *(u32x4*)&TG[s * 72 + e0] = *(const u32x4*)gx;
    *(u32x4*)&TG[s * 72 + e0 + 8] = *(const u32x4*)(gx + 8);
    *(u32x4*)&Sb[s * 72 + e0] = *(const u32x4*)gs;
    *(u32x4*)&Sb[s * 72 + e0 + 8] = *(const u32x4*)(gs + 8);
  }
  if (w == 0) {
    float a = -expf(A_log[h]) * dtb[((size_t)(b * 4096 + c * 64 + lane)) * 16 + h];
    float v = a;
#pragma unroll
    for (int d = 1; d < 64; d <<= 1) {
      float o = __shfl_up(v, d, 64);
      if (lane >= d) v += o;
    }
    csL[lane] = v;
    sdeL[lane] = expf(v);
  }
  __syncthreads();
  const int lr = lane & 15, lk = (lane >> 4) * 8;
  // G = C @ B^T (contract n)
  f32x4 g[4] = {};
#pragma unroll
  for (int kt = 0; kt < 64; kt += 32) {
    bf16x8 aF = *reinterpret_cast<const bf16x8*>(&Cb[(w * 16 + lr) * 72 + kt + lk]);
#pragma unroll
    for (int j = 0; j < 4; ++j) {
      bf16x8 bF = *reinterpret_cast<const bf16x8*>(&Bb[(j * 16 + lr) * 72 + kt + lk]);
      g[j] = __builtin_amdgcn_mfma_f32_16x16x32_bf16(aF, bF, g[j], 0, 0, 0);
    }
  }
  // transpose X: TG -> Xt
#pragma unroll
  for (int q = 0; q < 2; ++q) {
    const int p = lane;
    const int s0 = (q * 4 + w) * 8;
    u16x8 vx;
#pragma unroll
    for (int j = 0; j < 8; ++j) vx[j] = TG[(s0 + j) * 72 + p];
    *(u16x8*)&Xt[p * 72 + s0] = vx;
  }
  __syncthreads();
  // Gm = (G o L) -> TG ;  Cb *= sde[l]
#pragma unroll
  for (int j = 0; j < 4; ++j)
#pragma unroll
    for (int r = 0; r < 4; ++r) {
      const int l = w * 16 + (lane >> 4) * 4 + r;
      const int s = j * 16 + lr;
      const float gm = (l >= s) ? g[j][r] * expf(csL[l] - csL[s]) : 0.f;
      TG[l * 72 + s] = f2bf(gm);
    }
  {
    const int rl = tid >> 2, e0 = (tid & 3) * 16;
    const float sde = sdeL[rl];
#pragma unroll
    for (int half = 0; half < 2; ++half) {
      u16x8 v = *(u16x8*)&Cb[rl * 72 + e0 + half * 8];
#pragma unroll
      for (int j = 0; j < 8; ++j) v[j] = f2bf(bf2f(v[j]) * sde);
      *(u16x8*)&Cb[rl * 72 + e0 + half * 8] = v;
    }
  }
  __syncthreads();
  // Y = Gm @ Xt^T + Csde @ S^T
  f32x4 acc[4] = {};
#pragma unroll
  for (int kt = 0; kt < 64; kt += 32) {
    bf16x8 aG = *reinterpret_cast<const bf16x8*>(&TG[(w * 16 + lr) * 72 + kt + lk]);
    bf16x8 aC = *reinterpret_cast<const bf16x8*>(&Cb[(w * 16 + lr) * 72 + kt + lk]);
#pragma unroll
    for (int j = 0; j < 4; ++j) {
      bf16x8 bX = *reinterpret_cast<const bf16x8*>(&Xt[(j * 16 + lr) * 72 + kt + lk]);
      bf16x8 bS = *reinterpret_cast<const bf16x8*>(&Sb[(j * 16 + lr) * 72 + kt + lk]);
      acc[j] = __builtin_amdgcn_mfma_f32_16x16x32_bf16(aG, bX, acc[j], 0, 0, 0);
      acc[j] = __builtin_amdgcn_mfma_f32_16x16x32_bf16(aC, bS, acc[j], 0, 0, 0);
    }
  }
  // scrambled store: row = b*4096 + h*256 + c*4 + (l>>4), col = (l&15)*64 + p
  const size_t orow = (size_t)b * 4096 + h * 256 + c * 4 + w;
#pragma unroll
  for (int j = 0; j < 4; ++j)
#pragma unroll
    for (int r = 0; r < 4; ++r) {
      const int li = (lane >> 4) * 4 + r;
      y_bf[orow * 1024 + li * 64 + j * 16 + lr] = f2bf(acc[j][r]);
    }
}

// ---------------------------------------------------------------------------
extern "C" void kernel_launch(void* const* d_in, const int* in_sizes, int n_in,
                              void* d_out, int out_size, void* d_ws, size_t ws_size,
                              hipStream_t stream) {
  (void)in_sizes; (void)n_in; (void)out_size; (void)ws_size;
  const float* x = (const float*)d_in[0];
  const float* cosb = (const float*)d_in[1];
  const float* sinb = (const float*)d_in[2];
  const float* wq = (const float*)d_in[3];
  const float* wk = (const float*)d_in[4];
  const float* wv = (const float*)d_in[5];
  const float* wo = (const float*)d_in[6];
  const float* A_log = (const float*)d_in[7];
  const float* wdt = (const float*)d_in[8];
  const float* bdt = (const float*)d_in[9];

  float* out_y = (float*)d_out;        // (2,4096,1024) f32
  float* out_state = out_y + 8388608;  // (2,16,64,64) f32

  const size_t MBB = 1048576;
  char* ws = (char*)d_ws;
  unsigned short* x_bf = (unsigned short*)(ws);              // 16MB, reused as y_bf
  unsigned short* w_t = (unsigned short*)(ws + 16 * MBB);    // 8MB (q,k,v,o transposed)
  unsigned short* q_bf = (unsigned short*)(ws + 24 * MBB);   // 16MB
  unsigned short* k_bf = (unsigned short*)(ws + 40 * MBB);   // 16MB
  unsigned short* xv_bf = (unsigned short*)(ws + 56 * MBB);  // 16MB
  float* dtb = (float*)(ws + 72 * MBB);                      // 0.5MB
  unsigned short* wdt_bf = (unsigned short*)(ws + 73 * MBB); // 32KB
  unsigned short* chunk_states = (unsigned short*)(ws + 74 * MBB);  // 16MB bf16
  float* chunk_dec = (float*)(ws + 90 * MBB);                // 8KB
  unsigned short* inc_bf = (unsigned short*)(ws + 91 * MBB); // 16MB

  convert_bf16_kernel<<<8256, 256, 0, stream>>>(x, x_bf, 2097152, wdt, wdt_bf);
  transpose_w_kernel<<<dim3(32, 32, 4), dim3(32, 8), 0, stream>>>(wq, wk, wv, wo, w_t);
  dt_gemm_kernel<<<128, 256, 0, stream>>>(x_bf, wdt_bf, bdt, dtb);

  // fused QKV GEMM: N = 3072 (wq^T | wk^T | wv^T contiguous in w_t)
  gemm128_kernel<3><<<dim3(24, 64), 256, 0, stream>>>(
      x_bf, w_t, q_bf, k_bf, xv_bf, cosb, sinb, dtb);

  ssd_states_kernel<<<dim3(64, 16, 2), 256, 0, stream>>>(k_bf, xv_bf, dtb, A_log,
                                                         chunk_states, chunk_dec);
  scan_kernel<<<512, 256, 0, stream>>>(chunk_states, chunk_dec, inc_bf, out_state);
  ssd_y_kernel<<<dim3(64, 16, 2), 256, 0, stream>>>(q_bf, k_bf, xv_bf, inc_bf, dtb, A_log,
                                                    x_bf /*y_bf*/);

  gemm128_kernel<0><<<dim3(8, 64), 256, 0, stream>>>(
      x_bf /*y_bf*/, w_t + 3 * MBB, out_y, nullptr, nullptr, nullptr, nullptr, nullptr);
}